// Round 4
// baseline (682.017 us; speedup 1.0000x reference)
//
#include <hip/hip_runtime.h>
#include <hip/hip_bf16.h>
#include <stdint.h>

// Problem constants (fixed by reference): B=2, L=2048, D=1024, H=16, dk=64
#define SL 2048
#define SD 1024
#define SH 16
#define SB 2
#define DK 64

typedef __attribute__((ext_vector_type(4))) float f32x4;
typedef __attribute__((ext_vector_type(8))) short s16x8;   // 8 bf16 = 4 VGPRs
typedef __attribute__((ext_vector_type(4))) unsigned short u16x4;

__device__ __forceinline__ float bf2f(unsigned short u) {
    return __uint_as_float(((unsigned)u) << 16);
}
__device__ __forceinline__ unsigned short f2bf(float f) {
    unsigned u = __float_as_uint(f);
    return (unsigned short)((u + 0x7fffu + ((u >> 16) & 1u)) >> 16);
}
__device__ __forceinline__ f32x4 mfma16(s16x8 a, s16x8 b, f32x4 c) {
    return __builtin_amdgcn_mfma_f32_16x16x32_bf16(a, b, c, 0, 0, 0);
}
// build hi/lo bf16 fragments from 8 f32: hi+lo reproduces x to ~2^-17 rel
__device__ __forceinline__ void mk_hilo(f32x4 a, f32x4 b, s16x8& h, s16x8& l) {
#pragma unroll
    for (int i = 0; i < 4; ++i) {
        unsigned short ha = f2bf(a[i]);
        h[i] = (short)ha;  l[i] = (short)f2bf(a[i] - bf2f(ha));
        unsigned short hb = f2bf(b[i]);
        h[i + 4] = (short)hb;  l[i + 4] = (short)f2bf(b[i] - bf2f(hb));
    }
}

// ---------------- mask packing: int32 [L][L] -> bitmask [L][L/32] ----------
__global__ void pack_mask(const int* __restrict__ m, unsigned* __restrict__ bits) {
    long i = (long)blockIdx.x * blockDim.x + threadIdx.x;
    bool v = (m[i] != 0);
    unsigned long long bal = __ballot(v);
    int lane = threadIdx.x & 63;
    if ((lane & 31) == 0) bits[i >> 5] = (unsigned)(bal >> (lane & 32));
}

// ------- GEMM: C[M,N] = A[M,K] @ Bt[N,K]^T + bias[N], f32 via bf16 hi/lo ----
__global__ __launch_bounds__(256) void gemm_bt_f32(
    const float* __restrict__ A, const float* __restrict__ Bt,
    const float* __restrict__ bias, float* __restrict__ C,
    int M, int N, int K)
{
    __shared__ unsigned short Ah[128][72], Al[128][72];  // +8 pad kills bank conflicts
    __shared__ unsigned short Bh[128][72], Bl[128][72];
    const int tid = threadIdx.x;
    const int lane = tid & 63, w = tid >> 6;
    const int fr = lane & 15, fq = lane >> 4;
    const int row0 = blockIdx.y * 128, col0 = blockIdx.x * 128;
    const int moff = (w >> 1) * 64, noff = (w & 1) * 64;
    const int lr = tid >> 3;           // 0..31
    const int lc = (tid & 7) * 8;      // 0..56
    f32x4 acc[4][4] = {};
    for (int kt = 0; kt < K; kt += 64) {
        __syncthreads();
#pragma unroll
        for (int p = 0; p < 4; ++p) {
            int r = lr + p * 32;
            const float* as = &A[(size_t)(row0 + r) * K + kt + lc];
            f32x4 a0 = *(const f32x4*)as, a1 = *(const f32x4*)(as + 4);
            s16x8 h, l;
            mk_hilo(a0, a1, h, l);
            *(s16x8*)&Ah[r][lc] = h;  *(s16x8*)&Al[r][lc] = l;
            const float* bs = &Bt[(size_t)(col0 + r) * K + kt + lc];
            f32x4 b0 = *(const f32x4*)bs, b1 = *(const f32x4*)(bs + 4);
            mk_hilo(b0, b1, h, l);
            *(s16x8*)&Bh[r][lc] = h;  *(s16x8*)&Bl[r][lc] = l;
        }
        __syncthreads();
#pragma unroll
        for (int s = 0; s < 2; ++s) {
            s16x8 ah[4], al[4], bh[4], bl[4];
#pragma unroll
            for (int m = 0; m < 4; ++m) {
                ah[m] = *(const s16x8*)&Ah[moff + m * 16 + fr][s * 32 + fq * 8];
                al[m] = *(const s16x8*)&Al[moff + m * 16 + fr][s * 32 + fq * 8];
            }
#pragma unroll
            for (int n = 0; n < 4; ++n) {
                bh[n] = *(const s16x8*)&Bh[noff + n * 16 + fr][s * 32 + fq * 8];
                bl[n] = *(const s16x8*)&Bl[noff + n * 16 + fr][s * 32 + fq * 8];
            }
#pragma unroll
            for (int m = 0; m < 4; ++m)
#pragma unroll
                for (int n = 0; n < 4; ++n) {
                    acc[m][n] = mfma16(ah[m], bh[n], acc[m][n]);
                    acc[m][n] = mfma16(ah[m], bl[n], acc[m][n]);
                    acc[m][n] = mfma16(al[m], bh[n], acc[m][n]);
                }
        }
    }
#pragma unroll
    for (int n = 0; n < 4; ++n) {
        int c = col0 + noff + n * 16 + fr;
        float bv = bias[c];
#pragma unroll
        for (int m = 0; m < 4; ++m) {
            int r = row0 + moff + m * 16 + fq * 4;
#pragma unroll
            for (int j = 0; j < 4; ++j)
                C[(size_t)(r + j) * N + c] = acc[m][n][j] + bv;
        }
    }
}

// ---------------- flash attention (f32 q/k/v, hi/lo MFMA) ------------------
// block = 4 waves; each wave owns 16 q rows; block covers 64 q rows of one (b,h)
__global__ __launch_bounds__(256) void attn(
    const float* __restrict__ Qp, const float* __restrict__ Kp,
    const float* __restrict__ Vp, const unsigned* __restrict__ mbits,
    float* __restrict__ ctx)
{
    __shared__ unsigned short Kh[64][72], Klo[64][72];
    __shared__ unsigned short Vh[64][72], Vl[64][72];   // transposed: [d][k]
    __shared__ unsigned short Pl[4][16][72];            // per-wave P tile [q][k]
    __shared__ float stat[4][16];

    const int tid = threadIdx.x;
    const int lane = tid & 63, w = tid >> 6;
    const int fr = lane & 15, fq = lane >> 4;
    const int bid = blockIdx.x;
    const int nq = SL / 64;
    const int qb = bid % nq;
    const int bh_ = bid / nq;
    const int h = bh_ % SH, b = bh_ / SH;

    const int q0 = qb * 64 + w * 16;
    const int qrow = q0 + fr;
    const size_t qg = ((size_t)b * SL + qrow) * SD + h * DK;
    f32x4 q0a = *(const f32x4*)&Qp[qg + fq * 8];
    f32x4 q0b = *(const f32x4*)&Qp[qg + fq * 8 + 4];
    f32x4 q1a = *(const f32x4*)&Qp[qg + 32 + fq * 8];
    f32x4 q1b = *(const f32x4*)&Qp[qg + 32 + fq * 8 + 4];
    s16x8 qh0, ql0, qh1, ql1;
    mk_hilo(q0a, q0b, qh0, ql0);
    mk_hilo(q1a, q1b, qh1, ql1);

    f32x4 o[4] = {};
    float m_run = -1e30f, l_run = 0.f;
    const unsigned* mrow = mbits + (size_t)qrow * (SL >> 5);

    const int lr = tid >> 3, lc = (tid & 7) * 8;

    for (int kv = 0; kv < SL; kv += 64) {
        __syncthreads();                                   // prev PV done before restage
#pragma unroll
        for (int p = 0; p < 2; ++p) {
            int r = lr + p * 32;
            size_t g = ((size_t)b * SL + kv + r) * SD + h * DK + lc;
            f32x4 k0 = *(const f32x4*)&Kp[g], k1 = *(const f32x4*)&Kp[g + 4];
            s16x8 hh, ll;
            mk_hilo(k0, k1, hh, ll);
            *(s16x8*)&Kh[r][lc] = hh;  *(s16x8*)&Klo[r][lc] = ll;
            f32x4 v0 = *(const f32x4*)&Vp[g], v1 = *(const f32x4*)&Vp[g + 4];
#pragma unroll
            for (int i = 0; i < 4; ++i) {
                unsigned short vh_ = f2bf(v0[i]);
                Vh[lc + i][r] = vh_;  Vl[lc + i][r] = f2bf(v0[i] - bf2f(vh_));
                unsigned short vh2 = f2bf(v1[i]);
                Vh[lc + 4 + i][r] = vh2;  Vl[lc + 4 + i][r] = f2bf(v1[i] - bf2f(vh2));
            }
        }
        __syncthreads();

        // S^T tile: mfma(A=K rows, B=Q^T) -> lane holds q=fr, k = 16t + fq*4 + j
        f32x4 st[4];
#pragma unroll
        for (int t = 0; t < 4; ++t) {
            s16x8 kh0 = *(const s16x8*)&Kh[t * 16 + fr][fq * 8];
            s16x8 kh1 = *(const s16x8*)&Kh[t * 16 + fr][32 + fq * 8];
            s16x8 kl0 = *(const s16x8*)&Klo[t * 16 + fr][fq * 8];
            s16x8 kl1 = *(const s16x8*)&Klo[t * 16 + fr][32 + fq * 8];
            f32x4 z = {};
            z = mfma16(kh0, qh0, z);
            z = mfma16(kh1, qh1, z);
            z = mfma16(kh0, ql0, z);
            z = mfma16(kh1, ql1, z);
            z = mfma16(kl0, qh0, z);
            z = mfma16(kl1, qh1, z);
            st[t] = z;
        }

        unsigned mw0 = mrow[kv >> 5];
        unsigned mw1 = mrow[(kv >> 5) + 1];
        float sv[4][4];
        float mx = -1e30f;
#pragma unroll
        for (int t = 0; t < 4; ++t) {
            int kbase = t * 16 + fq * 4;
            unsigned word = (kbase & 32) ? mw1 : mw0;
#pragma unroll
            for (int j = 0; j < 4; ++j) {
                float x = st[t][j] * 0.125f;               // 1/sqrt(64)
                if (!((word >> ((kbase + j) & 31)) & 1u)) x = -10000.0f;
                sv[t][j] = x;
                mx = fmaxf(mx, x);
            }
        }
        mx = fmaxf(mx, __shfl_xor(mx, 16, 64));
        mx = fmaxf(mx, __shfl_xor(mx, 32, 64));
        float m_new = fmaxf(m_run, mx);
        float alpha = __expf(m_run - m_new);
        float ls = 0.f;
#pragma unroll
        for (int t = 0; t < 4; ++t) {
            u16x4 pb;
#pragma unroll
            for (int j = 0; j < 4; ++j) {
                float p = __expf(sv[t][j] - m_new);
                ls += p;
                pb[j] = f2bf(p);
            }
            *(u16x4*)&Pl[w][fr][t * 16 + fq * 4] = pb;
        }
        ls += __shfl_xor(ls, 16, 64);
        ls += __shfl_xor(ls, 32, 64);
        l_run = l_run * alpha + ls;
        m_run = m_new;
        if (lane < 16) stat[w][lane] = alpha;
        __syncthreads();                                   // P + alpha visible

        float al[4];
#pragma unroll
        for (int j = 0; j < 4; ++j) al[j] = stat[w][fq * 4 + j];
#pragma unroll
        for (int n = 0; n < 4; ++n)
#pragma unroll
            for (int j = 0; j < 4; ++j) o[n][j] *= al[j];

#pragma unroll
        for (int s = 0; s < 2; ++s) {
            s16x8 pa = *(const s16x8*)&Pl[w][fr][s * 32 + fq * 8];
#pragma unroll
            for (int n = 0; n < 4; ++n) {
                s16x8 vh = *(const s16x8*)&Vh[n * 16 + fr][s * 32 + fq * 8];
                s16x8 vl = *(const s16x8*)&Vl[n * 16 + fr][s * 32 + fq * 8];
                o[n] = mfma16(pa, vh, o[n]);
                o[n] = mfma16(pa, vl, o[n]);
            }
        }
    }

    __syncthreads();
    if (lane < 16) stat[w][lane] = l_run;
    __syncthreads();
    float li[4];
#pragma unroll
    for (int j = 0; j < 4; ++j) li[j] = stat[w][fq * 4 + j];
#pragma unroll
    for (int n = 0; n < 4; ++n)
#pragma unroll
        for (int j = 0; j < 4; ++j)
            ctx[((size_t)b * SL + q0 + fq * 4 + j) * SD + h * DK + n * 16 + fr] =
                o[n][j] / li[j];
}

extern "C" void kernel_launch(void* const* d_in, const int* in_sizes, int n_in,
                              void* d_out, int out_size, void* d_ws, size_t ws_size,
                              hipStream_t stream)
{
    const float* query = (const float*)d_in[0];
    const int* mask = (const int*)d_in[1];
    const float* Wq = (const float*)d_in[2];
    const float* bq = (const float*)d_in[3];
    const float* Wk = (const float*)d_in[4];
    const float* bk = (const float*)d_in[5];
    const float* Wv = (const float*)d_in[6];
    const float* bv = (const float*)d_in[7];
    const float* Wo = (const float*)d_in[8];
    const float* bo = (const float*)d_in[9];
    float* out = (float*)d_out;

    const size_t M = (size_t)SB * SL;           // 4096
    float* Qp = (float*)d_ws;
    float* Kp = Qp + M * SD;
    float* Vp = Kp + M * SD;
    float* ctx = Qp;                            // alias: Q consumed to regs before ctx write
    unsigned* mbits = (unsigned*)(Vp + M * SD);

    pack_mask<<<(SL * SL) / 256, 256, 0, stream>>>(mask, mbits);

    dim3 gg(SD / 128, M / 128);
    gemm_bt_f32<<<gg, 256, 0, stream>>>(query, Wq, bq, Qp, M, SD, SD);
    gemm_bt_f32<<<gg, 256, 0, stream>>>(query, Wk, bk, Kp, M, SD, SD);
    gemm_bt_f32<<<gg, 256, 0, stream>>>(query, Wv, bv, Vp, M, SD, SD);

    attn<<<SB * SH * (SL / 64), 256, 0, stream>>>(Qp, Kp, Vp, mbits, ctx);

    gemm_bt_f32<<<gg, 256, 0, stream>>>(ctx, Wo, bo, out, M, SD, SD);
}

// Round 5
// 673.299 us; speedup vs baseline: 1.0129x; 1.0129x over previous
//
#include <hip/hip_runtime.h>
#include <hip/hip_bf16.h>
#include <stdint.h>

// Problem constants (fixed by reference): B=2, L=2048, D=1024, H=16, dk=64
#define SL 2048
#define SD 1024
#define SH 16
#define SB 2
#define DK 64

typedef __attribute__((ext_vector_type(4))) float f32x4;
typedef __attribute__((ext_vector_type(8))) short s16x8;   // 8 bf16 = 4 VGPRs
typedef __attribute__((ext_vector_type(4))) unsigned short u16x4;

__device__ __forceinline__ float bf2f(unsigned short u) {
    return __uint_as_float(((unsigned)u) << 16);
}
__device__ __forceinline__ unsigned short f2bf(float f) {
    unsigned u = __float_as_uint(f);
    return (unsigned short)((u + 0x7fffu + ((u >> 16) & 1u)) >> 16);
}
__device__ __forceinline__ f32x4 mfma16(s16x8 a, s16x8 b, f32x4 c) {
    return __builtin_amdgcn_mfma_f32_16x16x32_bf16(a, b, c, 0, 0, 0);
}
// build hi/lo bf16 fragments from 8 f32: hi+lo reproduces x to ~2^-17 rel
__device__ __forceinline__ void mk_hilo(f32x4 a, f32x4 b, s16x8& h, s16x8& l) {
#pragma unroll
    for (int i = 0; i < 4; ++i) {
        unsigned short ha = f2bf(a[i]);
        h[i] = (short)ha;  l[i] = (short)f2bf(a[i] - bf2f(ha));
        unsigned short hb = f2bf(b[i]);
        h[i + 4] = (short)hb;  l[i + 4] = (short)f2bf(b[i] - bf2f(hb));
    }
}

// ---------------- f32 -> (hi, lo) bf16 planes, 8 elems/thread ---------------
__global__ void split_hilo(const float* __restrict__ x, unsigned short* __restrict__ h,
                           unsigned short* __restrict__ l, int n8) {
    int i = blockIdx.x * blockDim.x + threadIdx.x;
    if (i >= n8) return;
    const float* p = x + (size_t)i * 8;
    f32x4 a = *(const f32x4*)p, b = *(const f32x4*)(p + 4);
    s16x8 hh, ll;
    mk_hilo(a, b, hh, ll);
    *(s16x8*)(h + (size_t)i * 8) = hh;
    *(s16x8*)(l + (size_t)i * 8) = ll;
}

// ---------------- mask packing: int32 [L][L] -> bitmask [L][L/32] ----------
__global__ void pack_mask(const int* __restrict__ m, unsigned* __restrict__ bits) {
    long i = (long)blockIdx.x * blockDim.x + threadIdx.x;
    bool v = (m[i] != 0);
    unsigned long long bal = __ballot(v);
    int lane = threadIdx.x & 63;
    if ((lane & 31) == 0) bits[i >> 5] = (unsigned)(bal >> (lane & 32));
}

// ------- GEMM: C[M,N] = A @ Bt^T + bias, bf16 hi/lo planes in, 3-term MFMA --
// OUT=0: write hi/lo planes. OUT=1: write TRANSPOSED hi/lo planes [b][col][tok]
// (for V). OUT=2: write f32 (final output).
template <int OUT>
__global__ __launch_bounds__(256) void gemm_hl(
    const unsigned short* __restrict__ Ah_g, const unsigned short* __restrict__ Al_g,
    const unsigned short* __restrict__ Bh_g, const unsigned short* __restrict__ Bl_g,
    const float* __restrict__ bias,
    unsigned short* __restrict__ Ch, unsigned short* __restrict__ Cl,
    float* __restrict__ Cf, int M, int N, int K)
{
    __shared__ unsigned short Ahs[128][72], Als[128][72];  // +8 pad vs bank conflicts
    __shared__ unsigned short Bhs[128][72], Bls[128][72];
    const int tid = threadIdx.x;
    const int lane = tid & 63, w = tid >> 6;
    const int fr = lane & 15, fq = lane >> 4;
    const int row0 = blockIdx.y * 128, col0 = blockIdx.x * 128;
    const int moff = (w >> 1) * 64, noff = (w & 1) * 64;
    const int lr = tid >> 3;           // 0..31
    const int lc = (tid & 7) * 8;      // 0..56
    f32x4 acc[4][4] = {};
    for (int kt = 0; kt < K; kt += 64) {
        __syncthreads();
#pragma unroll
        for (int p = 0; p < 4; ++p) {
            int r = lr + p * 32;
            size_t ga = (size_t)(row0 + r) * K + kt + lc;
            size_t gb = (size_t)(col0 + r) * K + kt + lc;
            *(s16x8*)&Ahs[r][lc] = *(const s16x8*)&Ah_g[ga];
            *(s16x8*)&Als[r][lc] = *(const s16x8*)&Al_g[ga];
            *(s16x8*)&Bhs[r][lc] = *(const s16x8*)&Bh_g[gb];
            *(s16x8*)&Bls[r][lc] = *(const s16x8*)&Bl_g[gb];
        }
        __syncthreads();
#pragma unroll
        for (int s = 0; s < 2; ++s) {
            s16x8 ah[4], al[4], bh[4], bl[4];
#pragma unroll
            for (int m = 0; m < 4; ++m) {
                ah[m] = *(const s16x8*)&Ahs[moff + m * 16 + fr][s * 32 + fq * 8];
                al[m] = *(const s16x8*)&Als[moff + m * 16 + fr][s * 32 + fq * 8];
            }
#pragma unroll
            for (int n = 0; n < 4; ++n) {
                bh[n] = *(const s16x8*)&Bhs[noff + n * 16 + fr][s * 32 + fq * 8];
                bl[n] = *(const s16x8*)&Bls[noff + n * 16 + fr][s * 32 + fq * 8];
            }
#pragma unroll
            for (int m = 0; m < 4; ++m)
#pragma unroll
                for (int n = 0; n < 4; ++n) {
                    acc[m][n] = mfma16(ah[m], bh[n], acc[m][n]);
                    acc[m][n] = mfma16(ah[m], bl[n], acc[m][n]);
                    acc[m][n] = mfma16(al[m], bh[n], acc[m][n]);
                }
        }
    }
#pragma unroll
    for (int n = 0; n < 4; ++n) {
        int c = col0 + noff + n * 16 + fr;
        float bv = bias[c];
#pragma unroll
        for (int m = 0; m < 4; ++m) {
            int r = row0 + moff + m * 16 + fq * 4;
            if (OUT == 2) {
#pragma unroll
                for (int j = 0; j < 4; ++j)
                    Cf[(size_t)(r + j) * N + c] = acc[m][n][j] + bv;
            } else if (OUT == 0) {
#pragma unroll
                for (int j = 0; j < 4; ++j) {
                    float val = acc[m][n][j] + bv;
                    unsigned short hi = f2bf(val);
                    size_t o = (size_t)(r + j) * N + c;
                    Ch[o] = hi;
                    Cl[o] = f2bf(val - bf2f(hi));
                }
            } else {  // OUT==1: transposed planes [b][c][token], N==1024, token in [0,2048)
                u16x4 hv, lv;
#pragma unroll
                for (int j = 0; j < 4; ++j) {
                    float val = acc[m][n][j] + bv;
                    unsigned short hi = f2bf(val);
                    hv[j] = hi;
                    lv[j] = f2bf(val - bf2f(hi));
                }
                int b_ = r >> 11, tok = r & 2047;
                size_t o = ((size_t)b_ * SD + c) * SL + tok;
                *(u16x4*)&Ch[o] = hv;
                *(u16x4*)&Cl[o] = lv;
            }
        }
    }
}

// ---------------- flash attention (bf16 hi/lo planes in, ctx planes out) ----
// block = 4 waves; each wave owns 16 q rows; block covers 64 q rows of one (b,h)
__global__ __launch_bounds__(256) void attn(
    const unsigned short* __restrict__ Qh_g, const unsigned short* __restrict__ Ql_g,
    const unsigned short* __restrict__ Kh_g, const unsigned short* __restrict__ Kl_g,
    const unsigned short* __restrict__ Vth_g, const unsigned short* __restrict__ Vtl_g,
    const unsigned* __restrict__ mbits,
    unsigned short* __restrict__ ctxh, unsigned short* __restrict__ ctxl)
{
    __shared__ unsigned short Khs[64][72], Kls[64][72];
    __shared__ unsigned short Vhs[64][72], Vls[64][72];   // [d][token] (pre-transposed)
    __shared__ unsigned short Pl[4][16][72];              // per-wave P tile [q][k]
    __shared__ float stat[4][16];

    const int tid = threadIdx.x;
    const int lane = tid & 63, w = tid >> 6;
    const int fr = lane & 15, fq = lane >> 4;
    const int bid = blockIdx.x;
    const int nq = SL / 64;
    const int qb = bid % nq;
    const int bh_ = bid / nq;
    const int h = bh_ % SH, b = bh_ / SH;

    const int q0 = qb * 64 + w * 16;
    const int qrow = q0 + fr;
    const size_t qg = ((size_t)b * SL + qrow) * SD + h * DK;
    s16x8 qh0 = *(const s16x8*)&Qh_g[qg + fq * 8];
    s16x8 qh1 = *(const s16x8*)&Qh_g[qg + 32 + fq * 8];
    s16x8 ql0 = *(const s16x8*)&Ql_g[qg + fq * 8];
    s16x8 ql1 = *(const s16x8*)&Ql_g[qg + 32 + fq * 8];

    f32x4 o[4] = {};
    float m_run = -1e30f, l_run = 0.f;
    const unsigned* mrow = mbits + (size_t)qrow * (SL >> 5);

    const int sr = tid >> 2;          // 0..63
    const int sc = (tid & 3) * 8;     // 0,8,16,24

    for (int kv = 0; kv < SL; kv += 64) {
        __syncthreads();                                   // prev PV done before restage
        {
            size_t gk = ((size_t)b * SL + kv + sr) * SD + h * DK;
            *(s16x8*)&Khs[sr][sc]      = *(const s16x8*)&Kh_g[gk + sc];
            *(s16x8*)&Khs[sr][sc + 32] = *(const s16x8*)&Kh_g[gk + sc + 32];
            *(s16x8*)&Kls[sr][sc]      = *(const s16x8*)&Kl_g[gk + sc];
            *(s16x8*)&Kls[sr][sc + 32] = *(const s16x8*)&Kl_g[gk + sc + 32];
            size_t gv = ((size_t)b * SD + h * DK + sr) * SL + kv;
            *(s16x8*)&Vhs[sr][sc]      = *(const s16x8*)&Vth_g[gv + sc];
            *(s16x8*)&Vhs[sr][sc + 32] = *(const s16x8*)&Vth_g[gv + sc + 32];
            *(s16x8*)&Vls[sr][sc]      = *(const s16x8*)&Vtl_g[gv + sc];
            *(s16x8*)&Vls[sr][sc + 32] = *(const s16x8*)&Vtl_g[gv + sc + 32];
        }
        __syncthreads();

        // S^T tile: mfma(A=K rows, B=Q^T) -> lane holds q=fr, k = 16t + fq*4 + j
        f32x4 st[4];
#pragma unroll
        for (int t = 0; t < 4; ++t) {
            s16x8 kh0 = *(const s16x8*)&Khs[t * 16 + fr][fq * 8];
            s16x8 kh1 = *(const s16x8*)&Khs[t * 16 + fr][32 + fq * 8];
            s16x8 kl0 = *(const s16x8*)&Kls[t * 16 + fr][fq * 8];
            s16x8 kl1 = *(const s16x8*)&Kls[t * 16 + fr][32 + fq * 8];
            f32x4 z = {};
            z = mfma16(kh0, qh0, z);
            z = mfma16(kh1, qh1, z);
            z = mfma16(kh0, ql0, z);
            z = mfma16(kh1, ql1, z);
            z = mfma16(kl0, qh0, z);
            z = mfma16(kl1, qh1, z);
            st[t] = z;
        }

        unsigned mw0 = mrow[kv >> 5];
        unsigned mw1 = mrow[(kv >> 5) + 1];
        float sv[4][4];
        float mx = -1e30f;
#pragma unroll
        for (int t = 0; t < 4; ++t) {
            int kbase = t * 16 + fq * 4;
            unsigned word = (kbase & 32) ? mw1 : mw0;
#pragma unroll
            for (int j = 0; j < 4; ++j) {
                float x = st[t][j] * 0.125f;               // 1/sqrt(64)
                if (!((word >> ((kbase + j) & 31)) & 1u)) x = -10000.0f;
                sv[t][j] = x;
                mx = fmaxf(mx, x);
            }
        }
        mx = fmaxf(mx, __shfl_xor(mx, 16, 64));
        mx = fmaxf(mx, __shfl_xor(mx, 32, 64));
        float m_new = fmaxf(m_run, mx);
        float alpha = __expf(m_run - m_new);
        float ls = 0.f;
#pragma unroll
        for (int t = 0; t < 4; ++t) {
            u16x4 pb;
#pragma unroll
            for (int j = 0; j < 4; ++j) {
                float p = __expf(sv[t][j] - m_new);
                ls += p;
                pb[j] = f2bf(p);
            }
            *(u16x4*)&Pl[w][fr][t * 16 + fq * 4] = pb;
        }
        ls += __shfl_xor(ls, 16, 64);
        ls += __shfl_xor(ls, 32, 64);
        l_run = l_run * alpha + ls;
        m_run = m_new;
        if (lane < 16) stat[w][lane] = alpha;
        __syncthreads();                                   // P + alpha visible

        float al[4];
#pragma unroll
        for (int j = 0; j < 4; ++j) al[j] = stat[w][fq * 4 + j];
#pragma unroll
        for (int n = 0; n < 4; ++n)
#pragma unroll
            for (int j = 0; j < 4; ++j) o[n][j] *= al[j];

#pragma unroll
        for (int s = 0; s < 2; ++s) {
            s16x8 pa = *(const s16x8*)&Pl[w][fr][s * 32 + fq * 8];
#pragma unroll
            for (int n = 0; n < 4; ++n) {
                s16x8 vh = *(const s16x8*)&Vhs[n * 16 + fr][s * 32 + fq * 8];
                s16x8 vl = *(const s16x8*)&Vls[n * 16 + fr][s * 32 + fq * 8];
                o[n] = mfma16(pa, vh, o[n]);
                o[n] = mfma16(pa, vl, o[n]);
            }
        }
    }

    __syncthreads();
    if (lane < 16) stat[w][lane] = l_run;
    __syncthreads();
    float li[4];
#pragma unroll
    for (int j = 0; j < 4; ++j) li[j] = stat[w][fq * 4 + j];
#pragma unroll
    for (int n = 0; n < 4; ++n)
#pragma unroll
        for (int j = 0; j < 4; ++j) {
            float val = o[n][j] / li[j];
            size_t off = ((size_t)b * SL + q0 + fq * 4 + j) * SD + h * DK + n * 16 + fr;
            unsigned short hi = f2bf(val);
            ctxh[off] = hi;
            ctxl[off] = f2bf(val - bf2f(hi));
        }
}

extern "C" void kernel_launch(void* const* d_in, const int* in_sizes, int n_in,
                              void* d_out, int out_size, void* d_ws, size_t ws_size,
                              hipStream_t stream)
{
    const float* query = (const float*)d_in[0];
    const int* mask = (const int*)d_in[1];
    const float* Wq = (const float*)d_in[2];
    const float* bq = (const float*)d_in[3];
    const float* Wk = (const float*)d_in[4];
    const float* bk = (const float*)d_in[5];
    const float* Wv = (const float*)d_in[6];
    const float* bv = (const float*)d_in[7];
    const float* Wo = (const float*)d_in[8];
    const float* bo = (const float*)d_in[9];
    float* out = (float*)d_out;

    const size_t M = (size_t)SB * SL;           // 4096
    const size_t MD = M * SD;                   // 4 M elems
    const size_t WD = (size_t)SD * SD;          // 1 M elems

    unsigned short* p = (unsigned short*)d_ws;
    unsigned short* queryh = p;  p += MD;
    unsigned short* queryl = p;  p += MD;
    unsigned short* Wqh = p;  p += WD;
    unsigned short* Wql = p;  p += WD;
    unsigned short* Wkh = p;  p += WD;
    unsigned short* Wkl = p;  p += WD;
    unsigned short* Wvh = p;  p += WD;
    unsigned short* Wvl = p;  p += WD;
    unsigned short* Woh = p;  p += WD;
    unsigned short* Wol = p;  p += WD;
    unsigned short* Qh = p;  p += MD;
    unsigned short* Ql = p;  p += MD;
    unsigned short* Kh = p;  p += MD;
    unsigned short* Kl = p;  p += MD;
    unsigned short* Vth = p;  p += MD;
    unsigned short* Vtl = p;  p += MD;
    unsigned* mbits = (unsigned*)p;
    unsigned short* ctxh = queryh;   // alias: query planes consumed before attn writes
    unsigned short* ctxl = queryl;

    split_hilo<<<(int)(MD / 8 / 256), 256, 0, stream>>>(query, queryh, queryl, (int)(MD / 8));
    split_hilo<<<(int)(WD / 8 / 256), 256, 0, stream>>>(Wq, Wqh, Wql, (int)(WD / 8));
    split_hilo<<<(int)(WD / 8 / 256), 256, 0, stream>>>(Wk, Wkh, Wkl, (int)(WD / 8));
    split_hilo<<<(int)(WD / 8 / 256), 256, 0, stream>>>(Wv, Wvh, Wvl, (int)(WD / 8));
    split_hilo<<<(int)(WD / 8 / 256), 256, 0, stream>>>(Wo, Woh, Wol, (int)(WD / 8));

    pack_mask<<<(SL * SL) / 256, 256, 0, stream>>>(mask, mbits);

    dim3 gg(SD / 128, M / 128);
    gemm_hl<0><<<gg, 256, 0, stream>>>(queryh, queryl, Wqh, Wql, bq, Qh, Ql, nullptr, M, SD, SD);
    gemm_hl<0><<<gg, 256, 0, stream>>>(queryh, queryl, Wkh, Wkl, bk, Kh, Kl, nullptr, M, SD, SD);
    gemm_hl<1><<<gg, 256, 0, stream>>>(queryh, queryl, Wvh, Wvl, bv, Vth, Vtl, nullptr, M, SD, SD);

    attn<<<SB * SH * (SL / 64), 256, 0, stream>>>(Qh, Ql, Kh, Kl, Vth, Vtl, mbits, ctxh, ctxl);

    gemm_hl<2><<<gg, 256, 0, stream>>>(ctxh, ctxl, Woh, Wol, bo, nullptr, nullptr, out, M, SD, SD);
}

// Round 6
// 448.170 us; speedup vs baseline: 1.5218x; 1.5023x over previous
//
#include <hip/hip_runtime.h>
#include <hip/hip_bf16.h>
#include <stdint.h>

// Problem constants (fixed by reference): B=2, L=2048, D=1024, H=16, dk=64
#define SL 2048
#define SD 1024
#define SH 16
#define SB 2
#define DK 64

typedef __attribute__((ext_vector_type(4))) float f32x4;
typedef __attribute__((ext_vector_type(8))) short s16x8;   // 8 bf16 = 4 VGPRs
typedef __attribute__((ext_vector_type(4))) unsigned short u16x4;

__device__ __forceinline__ float bf2f(unsigned short u) {
    return __uint_as_float(((unsigned)u) << 16);
}
__device__ __forceinline__ unsigned short f2bf(float f) {
    unsigned u = __float_as_uint(f);
    return (unsigned short)((u + 0x7fffu + ((u >> 16) & 1u)) >> 16);
}
__device__ __forceinline__ f32x4 mfma16(s16x8 a, s16x8 b, f32x4 c) {
    return __builtin_amdgcn_mfma_f32_16x16x32_bf16(a, b, c, 0, 0, 0);
}
// async global->LDS, 16B per lane; LDS dest wave-uniform base + lane*16
__device__ __forceinline__ void gl16(const unsigned short* g, unsigned short* l) {
    __builtin_amdgcn_global_load_lds(
        (const __attribute__((address_space(1))) unsigned int*)g,
        (__attribute__((address_space(3))) unsigned int*)l, 16, 0, 0);
}
// build hi/lo bf16 fragments from 8 f32: hi+lo reproduces x to ~2^-17 rel
__device__ __forceinline__ void mk_hilo(f32x4 a, f32x4 b, s16x8& h, s16x8& l) {
#pragma unroll
    for (int i = 0; i < 4; ++i) {
        unsigned short ha = f2bf(a[i]);
        h[i] = (short)ha;  l[i] = (short)f2bf(a[i] - bf2f(ha));
        unsigned short hb = f2bf(b[i]);
        h[i + 4] = (short)hb;  l[i + 4] = (short)f2bf(b[i] - bf2f(hb));
    }
}

// ---------------- f32 -> (hi, lo) bf16 planes, 8 elems/thread ---------------
__global__ void split_hilo(const float* __restrict__ x, unsigned short* __restrict__ h,
                           unsigned short* __restrict__ l, int n8) {
    int i = blockIdx.x * blockDim.x + threadIdx.x;
    if (i >= n8) return;
    const float* p = x + (size_t)i * 8;
    f32x4 a = *(const f32x4*)p, b = *(const f32x4*)(p + 4);
    s16x8 hh, ll;
    mk_hilo(a, b, hh, ll);
    *(s16x8*)(h + (size_t)i * 8) = hh;
    *(s16x8*)(l + (size_t)i * 8) = ll;
}

// ---------------- mask packing: int32 [L][L] -> bitmask [L][L/32] ----------
__global__ void pack_mask(const int* __restrict__ m, unsigned* __restrict__ bits) {
    long i = (long)blockIdx.x * blockDim.x + threadIdx.x;
    bool v = (m[i] != 0);
    unsigned long long bal = __ballot(v);
    int lane = threadIdx.x & 63;
    if ((lane & 31) == 0) bits[i >> 5] = (unsigned)(bal >> (lane & 32));
}

// ------- GEMM: C[M,N] = A @ Bt^T + bias, bf16 hi/lo planes, 3-term MFMA -----
// global_load_lds staging + double-buffered prefetch (1 block/CU grid).
// OUT=0: hi/lo planes. OUT=1: transposed hi/lo planes [b][col][tok] (for V).
// OUT=2: f32 (final output).
template <int OUT>
__global__ __launch_bounds__(256) void gemm_hl(
    const unsigned short* __restrict__ Ah_g, const unsigned short* __restrict__ Al_g,
    const unsigned short* __restrict__ Bh_g, const unsigned short* __restrict__ Bl_g,
    const float* __restrict__ bias,
    unsigned short* __restrict__ Ch, unsigned short* __restrict__ Cl,
    float* __restrict__ Cf, int M, int N, int K)
{
    // 2 buffers x 4 planes x (128x64) bf16 = 128 KiB total (linear: gload_lds dest)
    __shared__ unsigned short Ahs[2][128][64], Als[2][128][64];
    __shared__ unsigned short Bhs[2][128][64], Bls[2][128][64];
    const int tid = threadIdx.x;
    const int lane = tid & 63, w = tid >> 6;
    const int fr = lane & 15, fq = lane >> 4;
    const int row0 = blockIdx.y * 128, col0 = blockIdx.x * 128;
    const int moff = (w >> 1) * 64, noff = (w & 1) * 64;
    const int l8 = lane >> 3;          // 0..7
    const int c8 = (lane & 7) * 8;     // 0..56
    f32x4 acc[4][4] = {};

    // stage one K-step tile (4 planes) into buffer `buf`; each wave covers 32 rows
#define STAGE(buf, kt)                                                        \
    {                                                                         \
        _Pragma("unroll")                                                     \
        for (int i = 0; i < 4; ++i) {                                         \
            int r = w * 32 + i * 8;              /* wave-uniform LDS row */   \
            size_t ga = (size_t)(row0 + r + l8) * K + (kt) + c8;              \
            size_t gb = (size_t)(col0 + r + l8) * K + (kt) + c8;              \
            gl16(&Ah_g[ga], &Ahs[buf][r][0]);                                 \
            gl16(&Al_g[ga], &Als[buf][r][0]);                                 \
            gl16(&Bh_g[gb], &Bhs[buf][r][0]);                                 \
            gl16(&Bl_g[gb], &Bls[buf][r][0]);                                 \
        }                                                                     \
    }

    STAGE(0, 0);
    __syncthreads();                     // vmcnt(0) drain: tile 0 resident
    const int nk = K / 64;
    for (int t = 0; t < nk; ++t) {
        const int buf = t & 1;
        if (t + 1 < nk) STAGE(buf ^ 1, (t + 1) * 64);   // prefetch: hidden under MFMAs
#pragma unroll
        for (int s = 0; s < 2; ++s) {
            s16x8 ah[4], al[4], bh[4], bl[4];
#pragma unroll
            for (int m = 0; m < 4; ++m) {
                ah[m] = *(const s16x8*)&Ahs[buf][moff + m * 16 + fr][s * 32 + fq * 8];
                al[m] = *(const s16x8*)&Als[buf][moff + m * 16 + fr][s * 32 + fq * 8];
            }
#pragma unroll
            for (int n = 0; n < 4; ++n) {
                bh[n] = *(const s16x8*)&Bhs[buf][noff + n * 16 + fr][s * 32 + fq * 8];
                bl[n] = *(const s16x8*)&Bls[buf][noff + n * 16 + fr][s * 32 + fq * 8];
            }
#pragma unroll
            for (int m = 0; m < 4; ++m)
#pragma unroll
                for (int n = 0; n < 4; ++n) {
                    acc[m][n] = mfma16(ah[m], bh[n], acc[m][n]);
                    acc[m][n] = mfma16(ah[m], bl[n], acc[m][n]);
                    acc[m][n] = mfma16(al[m], bh[n], acc[m][n]);
                }
        }
        __syncthreads();                 // drains prefetch vmcnt + protects buf reuse
    }
#undef STAGE

#pragma unroll
    for (int n = 0; n < 4; ++n) {
        int c = col0 + noff + n * 16 + fr;
        float bv = bias[c];
#pragma unroll
        for (int m = 0; m < 4; ++m) {
            int r = row0 + moff + m * 16 + fq * 4;
            if (OUT == 2) {
#pragma unroll
                for (int j = 0; j < 4; ++j)
                    Cf[(size_t)(r + j) * N + c] = acc[m][n][j] + bv;
            } else if (OUT == 0) {
#pragma unroll
                for (int j = 0; j < 4; ++j) {
                    float val = acc[m][n][j] + bv;
                    unsigned short hi = f2bf(val);
                    size_t o = (size_t)(r + j) * N + c;
                    Ch[o] = hi;
                    Cl[o] = f2bf(val - bf2f(hi));
                }
            } else {  // OUT==1: transposed planes [b][c][token], token in [0,2048)
                u16x4 hv, lv;
#pragma unroll
                for (int j = 0; j < 4; ++j) {
                    float val = acc[m][n][j] + bv;
                    unsigned short hi = f2bf(val);
                    hv[j] = hi;
                    lv[j] = f2bf(val - bf2f(hi));
                }
                int b_ = r >> 11, tok = r & 2047;
                size_t o = ((size_t)b_ * SD + c) * SL + tok;
                *(u16x4*)&Ch[o] = hv;
                *(u16x4*)&Cl[o] = lv;
            }
        }
    }
}

// ---------------- flash attention (bf16 hi/lo planes in, ctx planes out) ----
// block = 4 waves; each wave owns 16 q rows; block covers 64 q rows of one (b,h)
__global__ __launch_bounds__(256) void attn(
    const unsigned short* __restrict__ Qh_g, const unsigned short* __restrict__ Ql_g,
    const unsigned short* __restrict__ Kh_g, const unsigned short* __restrict__ Kl_g,
    const unsigned short* __restrict__ Vth_g, const unsigned short* __restrict__ Vtl_g,
    const unsigned* __restrict__ mbits,
    unsigned short* __restrict__ ctxh, unsigned short* __restrict__ ctxl)
{
    __shared__ unsigned short Khs[64][72], Kls[64][72];
    __shared__ unsigned short Vhs[64][72], Vls[64][72];   // [d][token] (pre-transposed)
    __shared__ unsigned short Pl[4][16][72];              // per-wave P tile [q][k]
    __shared__ float stat[4][16];

    const int tid = threadIdx.x;
    const int lane = tid & 63, w = tid >> 6;
    const int fr = lane & 15, fq = lane >> 4;
    const int bid = blockIdx.x;
    const int nq = SL / 64;
    const int qb = bid % nq;
    const int bh_ = bid / nq;
    const int h = bh_ % SH, b = bh_ / SH;

    const int q0 = qb * 64 + w * 16;
    const int qrow = q0 + fr;
    const size_t qg = ((size_t)b * SL + qrow) * SD + h * DK;
    s16x8 qh0 = *(const s16x8*)&Qh_g[qg + fq * 8];
    s16x8 qh1 = *(const s16x8*)&Qh_g[qg + 32 + fq * 8];
    s16x8 ql0 = *(const s16x8*)&Ql_g[qg + fq * 8];
    s16x8 ql1 = *(const s16x8*)&Ql_g[qg + 32 + fq * 8];

    f32x4 o[4] = {};
    float m_run = -1e30f, l_run = 0.f;
    const unsigned* mrow = mbits + (size_t)qrow * (SL >> 5);

    const int sr = tid >> 2;          // 0..63
    const int sc = (tid & 3) * 8;     // 0,8,16,24

    for (int kv = 0; kv < SL; kv += 64) {
        __syncthreads();                                   // prev PV done before restage
        {
            size_t gk = ((size_t)b * SL + kv + sr) * SD + h * DK;
            *(s16x8*)&Khs[sr][sc]      = *(const s16x8*)&Kh_g[gk + sc];
            *(s16x8*)&Khs[sr][sc + 32] = *(const s16x8*)&Kh_g[gk + sc + 32];
            *(s16x8*)&Kls[sr][sc]      = *(const s16x8*)&Kl_g[gk + sc];
            *(s16x8*)&Kls[sr][sc + 32] = *(const s16x8*)&Kl_g[gk + sc + 32];
            size_t gv = ((size_t)b * SD + h * DK + sr) * SL + kv;
            *(s16x8*)&Vhs[sr][sc]      = *(const s16x8*)&Vth_g[gv + sc];
            *(s16x8*)&Vhs[sr][sc + 32] = *(const s16x8*)&Vth_g[gv + sc + 32];
            *(s16x8*)&Vls[sr][sc]      = *(const s16x8*)&Vtl_g[gv + sc];
            *(s16x8*)&Vls[sr][sc + 32] = *(const s16x8*)&Vtl_g[gv + sc + 32];
        }
        __syncthreads();

        // S^T tile: mfma(A=K rows, B=Q^T) -> lane holds q=fr, k = 16t + fq*4 + j
        f32x4 st[4];
#pragma unroll
        for (int t = 0; t < 4; ++t) {
            s16x8 kh0 = *(const s16x8*)&Khs[t * 16 + fr][fq * 8];
            s16x8 kh1 = *(const s16x8*)&Khs[t * 16 + fr][32 + fq * 8];
            s16x8 kl0 = *(const s16x8*)&Kls[t * 16 + fr][fq * 8];
            s16x8 kl1 = *(const s16x8*)&Kls[t * 16 + fr][32 + fq * 8];
            f32x4 z = {};
            z = mfma16(kh0, qh0, z);
            z = mfma16(kh1, qh1, z);
            z = mfma16(kh0, ql0, z);
            z = mfma16(kh1, ql1, z);
            z = mfma16(kl0, qh0, z);
            z = mfma16(kl1, qh1, z);
            st[t] = z;
        }

        unsigned mw0 = mrow[kv >> 5];
        unsigned mw1 = mrow[(kv >> 5) + 1];
        float sv[4][4];
        float mx = -1e30f;
#pragma unroll
        for (int t = 0; t < 4; ++t) {
            int kbase = t * 16 + fq * 4;
            unsigned word = (kbase & 32) ? mw1 : mw0;
#pragma unroll
            for (int j = 0; j < 4; ++j) {
                float x = st[t][j] * 0.125f;               // 1/sqrt(64)
                if (!((word >> ((kbase + j) & 31)) & 1u)) x = -10000.0f;
                sv[t][j] = x;
                mx = fmaxf(mx, x);
            }
        }
        mx = fmaxf(mx, __shfl_xor(mx, 16, 64));
        mx = fmaxf(mx, __shfl_xor(mx, 32, 64));
        float m_new = fmaxf(m_run, mx);
        float alpha = __expf(m_run - m_new);
        float ls = 0.f;
#pragma unroll
        for (int t = 0; t < 4; ++t) {
            u16x4 pb;
#pragma unroll
            for (int j = 0; j < 4; ++j) {
                float p = __expf(sv[t][j] - m_new);
                ls += p;
                pb[j] = f2bf(p);
            }
            *(u16x4*)&Pl[w][fr][t * 16 + fq * 4] = pb;
        }
        ls += __shfl_xor(ls, 16, 64);
        ls += __shfl_xor(ls, 32, 64);
        l_run = l_run * alpha + ls;
        m_run = m_new;
        if (lane < 16) stat[w][lane] = alpha;
        __syncthreads();                                   // P + alpha visible

        float al[4];
#pragma unroll
        for (int j = 0; j < 4; ++j) al[j] = stat[w][fq * 4 + j];
#pragma unroll
        for (int n = 0; n < 4; ++n)
#pragma unroll
            for (int j = 0; j < 4; ++j) o[n][j] *= al[j];

#pragma unroll
        for (int s = 0; s < 2; ++s) {
            s16x8 pa = *(const s16x8*)&Pl[w][fr][s * 32 + fq * 8];
#pragma unroll
            for (int n = 0; n < 4; ++n) {
                s16x8 vh = *(const s16x8*)&Vhs[n * 16 + fr][s * 32 + fq * 8];
                s16x8 vl = *(const s16x8*)&Vls[n * 16 + fr][s * 32 + fq * 8];
                o[n] = mfma16(pa, vh, o[n]);
                o[n] = mfma16(pa, vl, o[n]);
            }
        }
    }

    __syncthreads();
    if (lane < 16) stat[w][lane] = l_run;
    __syncthreads();
    float li[4];
#pragma unroll
    for (int j = 0; j < 4; ++j) li[j] = stat[w][fq * 4 + j];
#pragma unroll
    for (int n = 0; n < 4; ++n)
#pragma unroll
        for (int j = 0; j < 4; ++j) {
            float val = o[n][j] / li[j];
            size_t off = ((size_t)b * SL + q0 + fq * 4 + j) * SD + h * DK + n * 16 + fr;
            unsigned short hi = f2bf(val);
            ctxh[off] = hi;
            ctxl[off] = f2bf(val - bf2f(hi));
        }
}

extern "C" void kernel_launch(void* const* d_in, const int* in_sizes, int n_in,
                              void* d_out, int out_size, void* d_ws, size_t ws_size,
                              hipStream_t stream)
{
    const float* query = (const float*)d_in[0];
    const int* mask = (const int*)d_in[1];
    const float* Wq = (const float*)d_in[2];
    const float* bq = (const float*)d_in[3];
    const float* Wk = (const float*)d_in[4];
    const float* bk = (const float*)d_in[5];
    const float* Wv = (const float*)d_in[6];
    const float* bv = (const float*)d_in[7];
    const float* Wo = (const float*)d_in[8];
    const float* bo = (const float*)d_in[9];
    float* out = (float*)d_out;

    const size_t M = (size_t)SB * SL;           // 4096
    const size_t MD = M * SD;                   // 4 M elems
    const size_t WD = (size_t)SD * SD;          // 1 M elems

    unsigned short* p = (unsigned short*)d_ws;
    unsigned short* queryh = p;  p += MD;
    unsigned short* queryl = p;  p += MD;
    unsigned short* Wqh = p;  p += WD;
    unsigned short* Wql = p;  p += WD;
    unsigned short* Wkh = p;  p += WD;
    unsigned short* Wkl = p;  p += WD;
    unsigned short* Wvh = p;  p += WD;
    unsigned short* Wvl = p;  p += WD;
    unsigned short* Woh = p;  p += WD;
    unsigned short* Wol = p;  p += WD;
    unsigned short* Qh = p;  p += MD;
    unsigned short* Ql = p;  p += MD;
    unsigned short* Kh = p;  p += MD;
    unsigned short* Kl = p;  p += MD;
    unsigned short* Vth = p;  p += MD;
    unsigned short* Vtl = p;  p += MD;
    unsigned* mbits = (unsigned*)p;
    unsigned short* ctxh = queryh;   // alias: query planes consumed before attn writes
    unsigned short* ctxl = queryl;

    split_hilo<<<(int)(MD / 8 / 256), 256, 0, stream>>>(query, queryh, queryl, (int)(MD / 8));
    split_hilo<<<(int)(WD / 8 / 256), 256, 0, stream>>>(Wq, Wqh, Wql, (int)(WD / 8));
    split_hilo<<<(int)(WD / 8 / 256), 256, 0, stream>>>(Wk, Wkh, Wkl, (int)(WD / 8));
    split_hilo<<<(int)(WD / 8 / 256), 256, 0, stream>>>(Wv, Wvh, Wvl, (int)(WD / 8));
    split_hilo<<<(int)(WD / 8 / 256), 256, 0, stream>>>(Wo, Woh, Wol, (int)(WD / 8));

    pack_mask<<<(SL * SL) / 256, 256, 0, stream>>>(mask, mbits);

    dim3 gg(SD / 128, M / 128);
    gemm_hl<0><<<gg, 256, 0, stream>>>(queryh, queryl, Wqh, Wql, bq, Qh, Ql, nullptr, M, SD, SD);
    gemm_hl<0><<<gg, 256, 0, stream>>>(queryh, queryl, Wkh, Wkl, bk, Kh, Kl, nullptr, M, SD, SD);
    gemm_hl<1><<<gg, 256, 0, stream>>>(queryh, queryl, Wvh, Wvl, bv, Vth, Vtl, nullptr, M, SD, SD);

    attn<<<SB * SH * (SL / 64), 256, 0, stream>>>(Qh, Ql, Kh, Kl, Vth, Vtl, mbits, ctxh, ctxl);

    gemm_hl<2><<<gg, 256, 0, stream>>>(ctxh, ctxl, Woh, Wol, bo, nullptr, nullptr, out, M, SD, SD);
}

// Round 7
// 407.997 us; speedup vs baseline: 1.6716x; 1.0985x over previous
//
#include <hip/hip_runtime.h>
#include <hip/hip_bf16.h>
#include <stdint.h>

// Problem constants (fixed by reference): B=2, L=2048, D=1024, H=16, dk=64
#define SL 2048
#define SD 1024
#define SH 16
#define SB 2
#define DK 64

typedef __attribute__((ext_vector_type(4))) float f32x4;
typedef __attribute__((ext_vector_type(8))) short s16x8;   // 8 bf16 = 4 VGPRs
typedef __attribute__((ext_vector_type(4))) unsigned short u16x4;

__device__ __forceinline__ float bf2f(unsigned short u) {
    return __uint_as_float(((unsigned)u) << 16);
}
__device__ __forceinline__ unsigned short f2bf(float f) {
    unsigned u = __float_as_uint(f);
    return (unsigned short)((u + 0x7fffu + ((u >> 16) & 1u)) >> 16);
}
__device__ __forceinline__ f32x4 mfma16(s16x8 a, s16x8 b, f32x4 c) {
    return __builtin_amdgcn_mfma_f32_16x16x32_bf16(a, b, c, 0, 0, 0);
}
// async global->LDS, 16B/lane; LDS dest = wave-uniform base + lane*16
__device__ __forceinline__ void gl16(const unsigned short* g, unsigned short* l) {
    __builtin_amdgcn_global_load_lds(
        (const __attribute__((address_space(1))) unsigned int*)g,
        (__attribute__((address_space(3))) unsigned int*)l, 16, 0, 0);
}
// build hi/lo bf16 fragments from 8 f32: hi+lo reproduces x to ~2^-17 rel
__device__ __forceinline__ void mk_hilo(f32x4 a, f32x4 b, s16x8& h, s16x8& l) {
#pragma unroll
    for (int i = 0; i < 4; ++i) {
        unsigned short ha = f2bf(a[i]);
        h[i] = (short)ha;  l[i] = (short)f2bf(a[i] - bf2f(ha));
        unsigned short hb = f2bf(b[i]);
        h[i + 4] = (short)hb;  l[i + 4] = (short)f2bf(b[i] - bf2f(hb));
    }
}
// swizzled fragment column (in shorts) within a 64-short (8-granule) row
__device__ __forceinline__ int swzcol(int s, int fq, int fr) {
    return (((s << 2) | fq) ^ (fr & 7)) << 3;
}

// ---------------- f32 -> (hi, lo) bf16 planes, 8 elems/thread ---------------
__global__ void split_hilo(const float* __restrict__ x, unsigned short* __restrict__ h,
                           unsigned short* __restrict__ l, int n8) {
    int i = blockIdx.x * blockDim.x + threadIdx.x;
    if (i >= n8) return;
    const float* p = x + (size_t)i * 8;
    f32x4 a = *(const f32x4*)p, b = *(const f32x4*)(p + 4);
    s16x8 hh, ll;
    mk_hilo(a, b, hh, ll);
    *(s16x8*)(h + (size_t)i * 8) = hh;
    *(s16x8*)(l + (size_t)i * 8) = ll;
}

// ---------------- mask packing: int32 [L][L] -> bitmask [L][L/32] ----------
__global__ void pack_mask(const int* __restrict__ m, unsigned* __restrict__ bits) {
    long i = (long)blockIdx.x * blockDim.x + threadIdx.x;
    bool v = (m[i] != 0);
    unsigned long long bal = __ballot(v);
    int lane = threadIdx.x & 63;
    if ((lane & 31) == 0) bits[i >> 5] = (unsigned)(bal >> (lane & 32));
}

// ------- shared GEMM core: 128x128 tile, BK=64, gl16 dbuf, 3-term hi/lo ----
template <typename Epi>
__device__ __forceinline__ void gemm_core(
    const unsigned short* __restrict__ Ah_g, const unsigned short* __restrict__ Al_g,
    const unsigned short* __restrict__ Bh_g, const unsigned short* __restrict__ Bl_g,
    int M, int N, int K, Epi&& epi)
{
    __shared__ unsigned short Ahs[2][128][64], Als[2][128][64];
    __shared__ unsigned short Bhs[2][128][64], Bls[2][128][64];
    const int tid = threadIdx.x;
    const int lane = tid & 63, w = tid >> 6;
    const int fr = lane & 15, fq = lane >> 4;
    const int row0 = blockIdx.y * 128, col0 = blockIdx.x * 128;
    const int moff = (w >> 1) * 64, noff = (w & 1) * 64;
    const int l8 = lane >> 3;          // 0..7
    const int c8 = (lane & 7) * 8;     // 0..56
    f32x4 acc[4][4] = {};

#define GSTAGE(buf, kt)                                                       \
    {                                                                         \
        _Pragma("unroll")                                                     \
        for (int i = 0; i < 4; ++i) {                                         \
            int r = w * 32 + i * 8;              /* wave-uniform LDS row */   \
            size_t ga = (size_t)(row0 + r + l8) * K + (kt) + c8;              \
            size_t gb = (size_t)(col0 + r + l8) * K + (kt) + c8;              \
            gl16(&Ah_g[ga], &Ahs[buf][r][0]);                                 \
            gl16(&Al_g[ga], &Als[buf][r][0]);                                 \
            gl16(&Bh_g[gb], &Bhs[buf][r][0]);                                 \
            gl16(&Bl_g[gb], &Bls[buf][r][0]);                                 \
        }                                                                     \
    }

    GSTAGE(0, 0);
    __syncthreads();
    const int nk = K / 64;
    for (int t = 0; t < nk; ++t) {
        const int buf = t & 1;
        if (t + 1 < nk) GSTAGE(buf ^ 1, (t + 1) * 64);
#pragma unroll
        for (int s = 0; s < 2; ++s) {
            s16x8 ah[4], al[4], bh[4], bl[4];
#pragma unroll
            for (int m = 0; m < 4; ++m) {
                ah[m] = *(const s16x8*)&Ahs[buf][moff + m * 16 + fr][s * 32 + fq * 8];
                al[m] = *(const s16x8*)&Als[buf][moff + m * 16 + fr][s * 32 + fq * 8];
            }
#pragma unroll
            for (int n = 0; n < 4; ++n) {
                bh[n] = *(const s16x8*)&Bhs[buf][noff + n * 16 + fr][s * 32 + fq * 8];
                bl[n] = *(const s16x8*)&Bls[buf][noff + n * 16 + fr][s * 32 + fq * 8];
            }
#pragma unroll
            for (int m = 0; m < 4; ++m)
#pragma unroll
                for (int n = 0; n < 4; ++n) {
                    acc[m][n] = mfma16(ah[m], bh[n], acc[m][n]);
                    acc[m][n] = mfma16(ah[m], bl[n], acc[m][n]);
                    acc[m][n] = mfma16(al[m], bh[n], acc[m][n]);
                }
        }
        __syncthreads();
    }
#undef GSTAGE
    epi(acc, row0 + moff, col0 + noff, fr, fq);
}

struct QKVArgs {
    const unsigned short* Wh[3];
    const unsigned short* Wl[3];
    const float* bias[3];
    unsigned short* Ch[3];
    unsigned short* Cl[3];   // Cl[2] unused (V is hi-only, transposed)
};

// fused Q/K/V projection: blockIdx.z selects weights + epilogue
__global__ __launch_bounds__(256) void gemm_qkv(
    const unsigned short* __restrict__ Ah_g, const unsigned short* __restrict__ Al_g,
    QKVArgs A, int M, int N, int K)
{
    const int z = blockIdx.z;
    const float* bias = A.bias[z];
    unsigned short* Ch = A.Ch[z];
    unsigned short* Cl = A.Cl[z];
    gemm_core(Ah_g, Al_g, A.Wh[z], A.Wl[z], M, N, K,
        [&](f32x4 (&acc)[4][4], int rbase, int cbase, int fr, int fq) {
#pragma unroll
            for (int n = 0; n < 4; ++n) {
                int c = cbase + n * 16 + fr;
                float bv = bias[c];
#pragma unroll
                for (int m = 0; m < 4; ++m) {
                    int r = rbase + m * 16 + fq * 4;
                    if (z == 2) {   // V: transposed hi-only planes [b][col][tok]
                        u16x4 hv;
#pragma unroll
                        for (int j = 0; j < 4; ++j) hv[j] = f2bf(acc[m][n][j] + bv);
                        int b_ = r >> 11, tok = r & 2047;
                        *(u16x4*)&Ch[((size_t)b_ * SD + c) * SL + tok] = hv;
                    } else {        // Q/K: hi/lo planes
#pragma unroll
                        for (int j = 0; j < 4; ++j) {
                            float val = acc[m][n][j] + bv;
                            unsigned short hi = f2bf(val);
                            size_t o = (size_t)(r + j) * N + c;
                            Ch[o] = hi;
                            Cl[o] = f2bf(val - bf2f(hi));
                        }
                    }
                }
            }
        });
}

// output projection: f32 result
__global__ __launch_bounds__(256) void gemm_o(
    const unsigned short* __restrict__ Ah_g, const unsigned short* __restrict__ Al_g,
    const unsigned short* __restrict__ Bh_g, const unsigned short* __restrict__ Bl_g,
    const float* __restrict__ bias, float* __restrict__ Cf, int M, int N, int K)
{
    gemm_core(Ah_g, Al_g, Bh_g, Bl_g, M, N, K,
        [&](f32x4 (&acc)[4][4], int rbase, int cbase, int fr, int fq) {
#pragma unroll
            for (int n = 0; n < 4; ++n) {
                int c = cbase + n * 16 + fr;
                float bv = bias[c];
#pragma unroll
                for (int m = 0; m < 4; ++m) {
                    int r = rbase + m * 16 + fq * 4;
#pragma unroll
                    for (int j = 0; j < 4; ++j)
                        Cf[(size_t)(r + j) * N + c] = acc[m][n][j] + bv;
                }
            }
        });
}

// ---------------- flash attention -----------------------------------------
// 4 waves/block, wave owns 16 q rows; gl16 swizzled staging, dbuf, 1 barrier/tile
__global__ __launch_bounds__(256) void attn(
    const unsigned short* __restrict__ Qh_g, const unsigned short* __restrict__ Ql_g,
    const unsigned short* __restrict__ Kh_g, const unsigned short* __restrict__ Kl_g,
    const unsigned short* __restrict__ Vth_g,
    const unsigned* __restrict__ mbits,
    unsigned short* __restrict__ ctxh, unsigned short* __restrict__ ctxl)
{
    __shared__ unsigned short Khs[2][64][64], Kls[2][64][64], Vhs[2][64][64];
    __shared__ unsigned short Pl[4][16][72];            // per-wave P tile (padded)

    const int tid = threadIdx.x;
    const int lane = tid & 63, w = tid >> 6;
    const int fr = lane & 15, fq = lane >> 4;

    // XCD swizzle (1024 % 8 == 0 -> simple form bijective): clusters the 32
    // q-blocks of 4 (b,h) per XCD so K/V panels stay L2-resident.
    const int bid0 = blockIdx.x;
    const int bid = (bid0 & 7) * (1024 >> 3) + (bid0 >> 3);
    const int nq = SL / 64;
    const int qb = bid % nq;
    const int bh_ = bid / nq;
    const int h = bh_ % SH, b = bh_ / SH;

    const int q0 = qb * 64 + w * 16;
    const int qrow = q0 + fr;
    const size_t qg = ((size_t)b * SL + qrow) * SD + h * DK;
    s16x8 qh0 = *(const s16x8*)&Qh_g[qg + fq * 8];
    s16x8 qh1 = *(const s16x8*)&Qh_g[qg + 32 + fq * 8];
    s16x8 ql0 = *(const s16x8*)&Ql_g[qg + fq * 8];
    s16x8 ql1 = *(const s16x8*)&Ql_g[qg + 32 + fq * 8];

    f32x4 o[4] = {};
    float m_run = -1e30f, l_run = 0.f;
    const unsigned* mrow = mbits + (size_t)qrow * (SL >> 5);

    const int srow = lane >> 3;                       // 0..7
    const int scolS = ((lane & 7) ^ srow) << 3;       // pre-swizzled src col (shorts)

    // stage one KV tile (Kh,Kl,Vh) into buffer `buf`; wave covers 16 rows/plane
#define ASTAGE(buf, kv)                                                       \
    {                                                                         \
        _Pragma("unroll")                                                     \
        for (int i = 0; i < 2; ++i) {                                         \
            int r0 = w * 16 + i * 8;                                          \
            int rr = r0 + srow;                                               \
            size_t gk = ((size_t)b * SL + (kv) + rr) * SD + h * DK + scolS;   \
            gl16(&Kh_g[gk], &Khs[buf][r0][0]);                                \
            gl16(&Kl_g[gk], &Kls[buf][r0][0]);                                \
            size_t gv = ((size_t)b * SD + h * DK + rr) * SL + (kv) + scolS;   \
            gl16(&Vth_g[gv], &Vhs[buf][r0][0]);                               \
        }                                                                     \
    }

    ASTAGE(0, 0);
    __syncthreads();
    int buf = 0;
    for (int kv = 0; kv < SL; kv += 64) {
        if (kv + 64 < SL) ASTAGE(buf ^ 1, kv + 64);    // prefetch next tile

        // S^T tile: mfma(A=K rows, B=Q^T) -> lane holds q=fr, k = 16t + fq*4 + j
        f32x4 st[4];
#pragma unroll
        for (int t = 0; t < 4; ++t) {
            const unsigned short* kb = &Khs[buf][t * 16 + fr][0];
            const unsigned short* lb = &Kls[buf][t * 16 + fr][0];
            s16x8 kh0 = *(const s16x8*)&kb[swzcol(0, fq, fr)];
            s16x8 kh1 = *(const s16x8*)&kb[swzcol(1, fq, fr)];
            s16x8 kl0 = *(const s16x8*)&lb[swzcol(0, fq, fr)];
            s16x8 kl1 = *(const s16x8*)&lb[swzcol(1, fq, fr)];
            f32x4 z = {};
            z = mfma16(kh0, qh0, z);
            z = mfma16(kh1, qh1, z);
            z = mfma16(kh0, ql0, z);
            z = mfma16(kh1, ql1, z);
            z = mfma16(kl0, qh0, z);
            z = mfma16(kl1, qh1, z);
            st[t] = z;
        }

        unsigned mw0 = mrow[kv >> 5];
        unsigned mw1 = mrow[(kv >> 5) + 1];
        float sv[4][4];
        float mx = -1e30f;
#pragma unroll
        for (int t = 0; t < 4; ++t) {
            int kbase = t * 16 + fq * 4;
            unsigned word = (kbase & 32) ? mw1 : mw0;
#pragma unroll
            for (int j = 0; j < 4; ++j) {
                float x = st[t][j] * 0.125f;               // 1/sqrt(64)
                if (!((word >> ((kbase + j) & 31)) & 1u)) x = -10000.0f;
                sv[t][j] = x;
                mx = fmaxf(mx, x);
            }
        }
        mx = fmaxf(mx, __shfl_xor(mx, 16, 64));
        mx = fmaxf(mx, __shfl_xor(mx, 32, 64));
        float m_new = fmaxf(m_run, mx);
        float alpha = __expf(m_run - m_new);
        float ls = 0.f;
#pragma unroll
        for (int t = 0; t < 4; ++t) {
            u16x4 pb;
#pragma unroll
            for (int j = 0; j < 4; ++j) {
                float p = __expf(sv[t][j] - m_new);
                ls += p;
                pb[j] = f2bf(p);
            }
            *(u16x4*)&Pl[w][fr][t * 16 + fq * 4] = pb;
        }
        ls += __shfl_xor(ls, 16, 64);
        ls += __shfl_xor(ls, 32, 64);
        l_run = l_run * alpha + ls;
        m_run = m_new;

        // rescale o by this row-group's alpha (broadcast via shfl, no LDS/barrier)
        float al[4];
#pragma unroll
        for (int j = 0; j < 4; ++j) al[j] = __shfl(alpha, fq * 4 + j, 64);
#pragma unroll
        for (int n = 0; n < 4; ++n)
#pragma unroll
            for (int j = 0; j < 4; ++j) o[n][j] *= al[j];

        // PV: P (same-wave LDS bounce, lgkmcnt-ordered) x V-hi
#pragma unroll
        for (int s = 0; s < 2; ++s) {
            s16x8 pa = *(const s16x8*)&Pl[w][fr][s * 32 + fq * 8];
#pragma unroll
            for (int n = 0; n < 4; ++n) {
                s16x8 vh = *(const s16x8*)&Vhs[buf][n * 16 + fr][swzcol(s, fq, fr)];
                o[n] = mfma16(pa, vh, o[n]);
            }
        }
        __syncthreads();           // all waves done with buf; prefetch drained
        buf ^= 1;
    }
#undef ASTAGE

    float li[4];
#pragma unroll
    for (int j = 0; j < 4; ++j) li[j] = __shfl(l_run, fq * 4 + j, 64);
#pragma unroll
    for (int n = 0; n < 4; ++n)
#pragma unroll
        for (int j = 0; j < 4; ++j) {
            float val = o[n][j] / li[j];
            size_t off = ((size_t)b * SL + q0 + fq * 4 + j) * SD + h * DK + n * 16 + fr;
            unsigned short hi = f2bf(val);
            ctxh[off] = hi;
            ctxl[off] = f2bf(val - bf2f(hi));
        }
}

extern "C" void kernel_launch(void* const* d_in, const int* in_sizes, int n_in,
                              void* d_out, int out_size, void* d_ws, size_t ws_size,
                              hipStream_t stream)
{
    const float* query = (const float*)d_in[0];
    const int* mask = (const int*)d_in[1];
    const float* Wq = (const float*)d_in[2];
    const float* bq = (const float*)d_in[3];
    const float* Wk = (const float*)d_in[4];
    const float* bk = (const float*)d_in[5];
    const float* Wv = (const float*)d_in[6];
    const float* bv = (const float*)d_in[7];
    const float* Wo = (const float*)d_in[8];
    const float* bo = (const float*)d_in[9];
    float* out = (float*)d_out;

    const size_t M = (size_t)SB * SL;           // 4096
    const size_t MD = M * SD;                   // 4 M elems
    const size_t WD = (size_t)SD * SD;          // 1 M elems

    unsigned short* p = (unsigned short*)d_ws;
    unsigned short* queryh = p;  p += MD;
    unsigned short* queryl = p;  p += MD;
    unsigned short* Wqh = p;  p += WD;
    unsigned short* Wql = p;  p += WD;
    unsigned short* Wkh = p;  p += WD;
    unsigned short* Wkl = p;  p += WD;
    unsigned short* Wvh = p;  p += WD;
    unsigned short* Wvl = p;  p += WD;
    unsigned short* Woh = p;  p += WD;
    unsigned short* Wol = p;  p += WD;
    unsigned short* Qh = p;  p += MD;
    unsigned short* Ql = p;  p += MD;
    unsigned short* Kh = p;  p += MD;
    unsigned short* Kl = p;  p += MD;
    unsigned short* Vth = p;  p += MD;
    unsigned* mbits = (unsigned*)p;
    unsigned short* ctxh = queryh;   // alias: query planes consumed before attn writes
    unsigned short* ctxl = queryl;

    split_hilo<<<(int)(MD / 8 / 256), 256, 0, stream>>>(query, queryh, queryl, (int)(MD / 8));
    split_hilo<<<(int)(WD / 8 / 256), 256, 0, stream>>>(Wq, Wqh, Wql, (int)(WD / 8));
    split_hilo<<<(int)(WD / 8 / 256), 256, 0, stream>>>(Wk, Wkh, Wkl, (int)(WD / 8));
    split_hilo<<<(int)(WD / 8 / 256), 256, 0, stream>>>(Wv, Wvh, Wvl, (int)(WD / 8));
    split_hilo<<<(int)(WD / 8 / 256), 256, 0, stream>>>(Wo, Woh, Wol, (int)(WD / 8));

    pack_mask<<<(SL * SL) / 256, 256, 0, stream>>>(mask, mbits);

    QKVArgs A;
    A.Wh[0] = Wqh; A.Wl[0] = Wql; A.bias[0] = bq; A.Ch[0] = Qh;  A.Cl[0] = Ql;
    A.Wh[1] = Wkh; A.Wl[1] = Wkl; A.bias[1] = bk; A.Ch[1] = Kh;  A.Cl[1] = Kl;
    A.Wh[2] = Wvh; A.Wl[2] = Wvl; A.bias[2] = bv; A.Ch[2] = Vth; A.Cl[2] = nullptr;

    dim3 gq(SD / 128, M / 128, 3);
    gemm_qkv<<<gq, 256, 0, stream>>>(queryh, queryl, A, (int)M, SD, SD);

    attn<<<SB * SH * (SL / 64), 256, 0, stream>>>(Qh, Ql, Kh, Kl, Vth, mbits, ctxh, ctxl);

    dim3 gg(SD / 128, M / 128);
    gemm_o<<<gg, 256, 0, stream>>>(ctxh, ctxl, Woh, Wol, bo, out, (int)M, SD, SD);
}

// Round 8
// 367.753 us; speedup vs baseline: 1.8546x; 1.1094x over previous
//
#include <hip/hip_runtime.h>
#include <hip/hip_bf16.h>
#include <stdint.h>

// Problem constants (fixed by reference): B=2, L=2048, D=1024, H=16, dk=64
#define SL 2048
#define SD 1024
#define SH 16
#define SB 2
#define DK 64

// scores are computed in exp2-domain: Q pre-scaled by 1/sqrt(dk) * log2(e)
#define QSCALE 0.1803368801111244f
#define NEGBIG -20000.0f

typedef __attribute__((ext_vector_type(4))) float f32x4;
typedef __attribute__((ext_vector_type(8))) short s16x8;   // 8 bf16 = 4 VGPRs
typedef __attribute__((ext_vector_type(4))) unsigned short u16x4;

__device__ __forceinline__ float bf2f(unsigned short u) {
    return __uint_as_float(((unsigned)u) << 16);
}
__device__ __forceinline__ unsigned short f2bf(float f) {
    unsigned u = __float_as_uint(f);
    return (unsigned short)((u + 0x7fffu + ((u >> 16) & 1u)) >> 16);
}
__device__ __forceinline__ f32x4 mfma16(s16x8 a, s16x8 b, f32x4 c) {
    return __builtin_amdgcn_mfma_f32_16x16x32_bf16(a, b, c, 0, 0, 0);
}
// async global->LDS, 16B/lane; LDS dest = wave-uniform base + lane*16
__device__ __forceinline__ void gl16(const unsigned short* g, unsigned short* l) {
    __builtin_amdgcn_global_load_lds(
        (const __attribute__((address_space(1))) unsigned int*)g,
        (__attribute__((address_space(3))) unsigned int*)l, 16, 0, 0);
}
// pack 2 f32 -> 2 bf16 in one u32 (lo = a, hi = b), RNE
__device__ __forceinline__ unsigned cvtpk(float a, float b) {
    unsigned r;
    asm("v_cvt_pk_bf16_f32 %0, %1, %2" : "=v"(r) : "v"(a), "v"(b));
    return r;
}
// build hi/lo bf16 fragments from 8 f32: hi+lo reproduces x to ~2^-17 rel
__device__ __forceinline__ void mk_hilo(f32x4 a, f32x4 b, s16x8& h, s16x8& l) {
#pragma unroll
    for (int i = 0; i < 4; ++i) {
        unsigned short ha = f2bf(a[i]);
        h[i] = (short)ha;  l[i] = (short)f2bf(a[i] - bf2f(ha));
        unsigned short hb = f2bf(b[i]);
        h[i + 4] = (short)hb;  l[i + 4] = (short)f2bf(b[i] - bf2f(hb));
    }
}
// XCD-aware block swizzle (bijective: grid x*y = 256, %8 == 0)
__device__ __forceinline__ void xcd_map(int& bx, int& by) {
    int nx = gridDim.x, n = nx * gridDim.y;
    int f = blockIdx.y * nx + blockIdx.x;
    int v = (f & 7) * (n >> 3) + (f >> 3);
    bx = v % nx;  by = v / nx;
}

// ---------------- fused f32 -> (hi,lo) planes for query + 4 weights ---------
struct SplitArgs {
    const float* src[5];
    unsigned short* h[5];
    unsigned short* l[5];
};
__global__ void split_all(SplitArgs S) {
    int i = blockIdx.x * blockDim.x + threadIdx.x;   // 8-elem units
    int z, off;
    if (i < (1 << 19)) { z = 0; off = i; }                       // query: 4M elems
    else { int j = i - (1 << 19); z = 1 + (j >> 17); off = j & ((1 << 17) - 1); }
    const float* p = S.src[z] + (size_t)off * 8;
    f32x4 a = *(const f32x4*)p, b = *(const f32x4*)(p + 4);
    s16x8 hh, ll;
    mk_hilo(a, b, hh, ll);
    *(s16x8*)(S.h[z] + (size_t)off * 8) = hh;
    *(s16x8*)(S.l[z] + (size_t)off * 8) = ll;
}

// ---------------- mask packing: int32 [L][L] -> bitmask [L][L/32] ----------
__global__ void pack_mask(const int* __restrict__ m, unsigned* __restrict__ bits) {
    long i = (long)blockIdx.x * blockDim.x + threadIdx.x;
    bool v = (m[i] != 0);
    unsigned long long bal = __ballot(v);
    int lane = threadIdx.x & 63;
    if ((lane & 31) == 0) bits[i >> 5] = (unsigned)(bal >> (lane & 32));
}

// ------- shared GEMM core: 128x128 tile, gl16 dbuf, T2-swizzled LDS --------
template <int BK, typename Epi>
__device__ __forceinline__ void gemm_core(
    const unsigned short* __restrict__ Ah_g, const unsigned short* __restrict__ Al_g,
    const unsigned short* __restrict__ Bh_g, const unsigned short* __restrict__ Bl_g,
    int K, int row0, int col0, Epi&& epi)
{
    __shared__ unsigned short Ahs[2][128][BK], Als[2][128][BK];
    __shared__ unsigned short Bhs[2][128][BK], Bls[2][128][BK];
    constexpr int GR = BK / 8;          // 16B granules per LDS row
    constexpr int RPG = 64 / GR;        // rows covered by one gl16
    const int tid = threadIdx.x;
    const int lane = tid & 63, w = tid >> 6;
    const int fr = lane & 15, fq = lane >> 4;
    const int moff = (w >> 1) * 64, noff = (w & 1) * 64;
    const int lrow = lane / GR;
    const int lg = (lane % GR) ^ (lrow & (GR - 1));   // pre-swizzled source granule
    f32x4 acc[4][4] = {};

    auto stage = [&](int buf, int kt) {
#pragma unroll
        for (int i = 0; i < 32 / RPG; ++i) {
            int r0 = w * 32 + i * RPG;               // wave-uniform LDS row base
            size_t ga = (size_t)(row0 + r0 + lrow) * K + kt + lg * 8;
            size_t gb = (size_t)(col0 + r0 + lrow) * K + kt + lg * 8;
            gl16(&Ah_g[ga], &Ahs[buf][r0][0]);
            gl16(&Al_g[ga], &Als[buf][r0][0]);
            gl16(&Bh_g[gb], &Bhs[buf][r0][0]);
            gl16(&Bl_g[gb], &Bls[buf][r0][0]);
        }
    };

    stage(0, 0);
    __syncthreads();
    const int nk = K / BK;
    for (int t = 0; t < nk; ++t) {
        const int buf = t & 1;
        if (t + 1 < nk) stage(buf ^ 1, (t + 1) * BK);
#pragma unroll
        for (int s = 0; s < BK / 32; ++s) {
            s16x8 ah[4], al[4], bh[4], bl[4];
#pragma unroll
            for (int m = 0; m < 4; ++m) {
                int row = moff + m * 16 + fr;
                int col = ((s * 4 + fq) ^ (fr & (GR - 1))) * 8;   // T2 swizzled read
                ah[m] = *(const s16x8*)&Ahs[buf][row][col];
                al[m] = *(const s16x8*)&Als[buf][row][col];
            }
#pragma unroll
            for (int n = 0; n < 4; ++n) {
                int row = noff + n * 16 + fr;
                int col = ((s * 4 + fq) ^ (fr & (GR - 1))) * 8;
                bh[n] = *(const s16x8*)&Bhs[buf][row][col];
                bl[n] = *(const s16x8*)&Bls[buf][row][col];
            }
#pragma unroll
            for (int m = 0; m < 4; ++m)
#pragma unroll
                for (int n = 0; n < 4; ++n) {
                    acc[m][n] = mfma16(ah[m], bh[n], acc[m][n]);
                    acc[m][n] = mfma16(ah[m], bl[n], acc[m][n]);
                    acc[m][n] = mfma16(al[m], bh[n], acc[m][n]);
                }
        }
        __syncthreads();
    }
    epi(acc, row0 + moff, col0 + noff, fr, fq);
}

struct QKVArgs {
    const unsigned short* Wh[3];
    const unsigned short* Wl[3];
    const float* bias[3];
    unsigned short* Ch[3];
    unsigned short* Cl[3];   // Cl[2] unused (V is hi-only, transposed)
};

// fused Q/K/V projection: blockIdx.z selects weights + epilogue
__global__ __launch_bounds__(256) void gemm_qkv(
    const unsigned short* __restrict__ Ah_g, const unsigned short* __restrict__ Al_g,
    QKVArgs A, int K)
{
    int bx, by;  xcd_map(bx, by);
    const int z = blockIdx.z;
    const float* bias = A.bias[z];
    unsigned short* Ch = A.Ch[z];
    unsigned short* Cl = A.Cl[z];
    gemm_core<32>(Ah_g, Al_g, A.Wh[z], A.Wl[z], K, by * 128, bx * 128,
        [&](f32x4 (&acc)[4][4], int rbase, int cbase, int fr, int fq) {
#pragma unroll
            for (int n = 0; n < 4; ++n) {
                int c = cbase + n * 16 + fr;
                float bv = bias[c];
#pragma unroll
                for (int m = 0; m < 4; ++m) {
                    int r = rbase + m * 16 + fq * 4;
                    if (z == 2) {   // V: transposed hi-only planes [b][col][tok]
                        u16x4 hv;
#pragma unroll
                        for (int j = 0; j < 4; ++j) hv[j] = f2bf(acc[m][n][j] + bv);
                        int b_ = r >> 11, tok = r & 2047;
                        *(u16x4*)&Ch[((size_t)b_ * SD + c) * SL + tok] = hv;
                    } else {        // Q/K hi/lo planes; Q pre-scaled to exp2 domain
#pragma unroll
                        for (int j = 0; j < 4; ++j) {
                            float val = acc[m][n][j] + bv;
                            if (z == 0) val *= QSCALE;
                            unsigned short hi = f2bf(val);
                            size_t o = (size_t)(r + j) * SD + c;
                            Ch[o] = hi;
                            Cl[o] = f2bf(val - bf2f(hi));
                        }
                    }
                }
            }
        });
}

// output projection: f32 result
__global__ __launch_bounds__(256) void gemm_o(
    const unsigned short* __restrict__ Ah_g, const unsigned short* __restrict__ Al_g,
    const unsigned short* __restrict__ Bh_g, const unsigned short* __restrict__ Bl_g,
    const float* __restrict__ bias, float* __restrict__ Cf, int K)
{
    int bx, by;  xcd_map(bx, by);
    gemm_core<64>(Ah_g, Al_g, Bh_g, Bl_g, K, by * 128, bx * 128,
        [&](f32x4 (&acc)[4][4], int rbase, int cbase, int fr, int fq) {
#pragma unroll
            for (int n = 0; n < 4; ++n) {
                int c = cbase + n * 16 + fr;
                float bv = bias[c];
#pragma unroll
                for (int m = 0; m < 4; ++m) {
                    int r = rbase + m * 16 + fq * 4;
#pragma unroll
                    for (int j = 0; j < 4; ++j)
                        Cf[(size_t)(r + j) * SD + c] = acc[m][n][j] + bv;
                }
            }
        });
}

// swizzled fragment column (in shorts) within a 64-short (8-granule) row
__device__ __forceinline__ int swzcol(int s, int fq, int fr) {
    return (((s << 2) | fq) ^ (fr & 7)) << 3;
}

// ---------------- flash attention (exp2-domain online softmax) -------------
// 4 waves/block, wave owns 16 q rows; gl16 swizzled staging, dbuf, 1 barrier/tile
__global__ __launch_bounds__(256) void attn(
    const unsigned short* __restrict__ Qh_g, const unsigned short* __restrict__ Ql_g,
    const unsigned short* __restrict__ Kh_g, const unsigned short* __restrict__ Kl_g,
    const unsigned short* __restrict__ Vth_g,
    const unsigned* __restrict__ mbits,
    unsigned short* __restrict__ ctxh, unsigned short* __restrict__ ctxl)
{
    __shared__ unsigned short Khs[2][64][64], Kls[2][64][64], Vhs[2][64][64];
    __shared__ unsigned short Pl[4][16][72];            // per-wave P tile (padded)

    const int tid = threadIdx.x;
    const int lane = tid & 63, w = tid >> 6;
    const int fr = lane & 15, fq = lane >> 4;

    const int bid0 = blockIdx.x;
    const int bid = (bid0 & 7) * (1024 >> 3) + (bid0 >> 3);   // XCD swizzle
    const int nq = SL / 64;
    const int qb = bid % nq;
    const int bh_ = bid / nq;
    const int h = bh_ % SH, b = bh_ / SH;

    const int q0 = qb * 64 + w * 16;
    const int qrow = q0 + fr;
    const size_t qg = ((size_t)b * SL + qrow) * SD + h * DK;
    s16x8 qh0 = *(const s16x8*)&Qh_g[qg + fq * 8];
    s16x8 qh1 = *(const s16x8*)&Qh_g[qg + 32 + fq * 8];
    s16x8 ql0 = *(const s16x8*)&Ql_g[qg + fq * 8];
    s16x8 ql1 = *(const s16x8*)&Ql_g[qg + 32 + fq * 8];

    f32x4 o[4] = {};
    float m_run = -1e30f, l_run = 0.f;
    const unsigned* mrow = mbits + (size_t)qrow * (SL >> 5);

    const int srow = lane >> 3;                       // 0..7
    const int scolS = ((lane & 7) ^ srow) << 3;       // pre-swizzled src col (shorts)

#define ASTAGE(buf, kv)                                                       \
    {                                                                         \
        _Pragma("unroll")                                                     \
        for (int i = 0; i < 2; ++i) {                                         \
            int r0 = w * 16 + i * 8;                                          \
            int rr = r0 + srow;                                               \
            size_t gk = ((size_t)b * SL + (kv) + rr) * SD + h * DK + scolS;   \
            gl16(&Kh_g[gk], &Khs[buf][r0][0]);                                \
            gl16(&Kl_g[gk], &Kls[buf][r0][0]);                                \
            size_t gv = ((size_t)b * SD + h * DK + rr) * SL + (kv) + scolS;   \
            gl16(&Vth_g[gv], &Vhs[buf][r0][0]);                               \
        }                                                                     \
    }

    ASTAGE(0, 0);
    __syncthreads();
    int buf = 0;
    for (int kv = 0; kv < SL; kv += 64) {
        if (kv + 64 < SL) ASTAGE(buf ^ 1, kv + 64);    // prefetch next tile

        // S^T tile: mfma(A=K rows, B=Q^T) -> lane holds q=fr, k = 16t + fq*4 + j
        f32x4 st[4];
#pragma unroll
        for (int t = 0; t < 4; ++t) {
            const unsigned short* kb = &Khs[buf][t * 16 + fr][0];
            const unsigned short* lb = &Kls[buf][t * 16 + fr][0];
            s16x8 kh0 = *(const s16x8*)&kb[swzcol(0, fq, fr)];
            s16x8 kh1 = *(const s16x8*)&kb[swzcol(1, fq, fr)];
            s16x8 kl0 = *(const s16x8*)&lb[swzcol(0, fq, fr)];
            s16x8 kl1 = *(const s16x8*)&lb[swzcol(1, fq, fr)];
            f32x4 z = {};
            z = mfma16(kh0, qh0, z);
            z = mfma16(kh1, qh1, z);
            z = mfma16(kh0, ql0, z);
            z = mfma16(kh1, ql1, z);
            z = mfma16(kl0, qh0, z);
            z = mfma16(kl1, qh1, z);
            st[t] = z;
        }

        unsigned mw0 = mrow[kv >> 5];
        unsigned mw1 = mrow[(kv >> 5) + 1];
        float sv[4][4], tm[4];
#pragma unroll
        for (int t = 0; t < 4; ++t) {
            int kbase = t * 16 + fq * 4;
            unsigned word = (kbase & 32) ? mw1 : mw0;
#pragma unroll
            for (int j = 0; j < 4; ++j) {
                float x = st[t][j];                        // already exp2-domain
                if (!((word >> ((kbase + j) & 31)) & 1u)) x = NEGBIG;
                sv[t][j] = x;
            }
            tm[t] = fmaxf(fmaxf(sv[t][0], sv[t][1]), fmaxf(sv[t][2], sv[t][3]));
        }
        float mx = fmaxf(fmaxf(tm[0], tm[1]), fmaxf(tm[2], tm[3]));
        mx = fmaxf(mx, __shfl_xor(mx, 16, 64));
        mx = fmaxf(mx, __shfl_xor(mx, 32, 64));

        // defer-max (T13): only rescale when some row max grew by > 8 (P <= 256)
        if (__any(mx > m_run + 8.0f)) {
            float m_new = fmaxf(m_run, mx);
            float alpha = exp2f(m_run - m_new);
            float al[4];
#pragma unroll
            for (int j = 0; j < 4; ++j) al[j] = __shfl(alpha, fq * 4 + j, 64);
#pragma unroll
            for (int n = 0; n < 4; ++n)
#pragma unroll
                for (int j = 0; j < 4; ++j) o[n][j] *= al[j];
            l_run *= alpha;
            m_run = m_new;
        }

        float ls = 0.f;
#pragma unroll
        for (int t = 0; t < 4; ++t) {
            float p0 = exp2f(sv[t][0] - m_run);
            float p1 = exp2f(sv[t][1] - m_run);
            float p2 = exp2f(sv[t][2] - m_run);
            float p3 = exp2f(sv[t][3] - m_run);
            ls += (p0 + p1) + (p2 + p3);
            *(uint2*)&Pl[w][fr][t * 16 + fq * 4] = make_uint2(cvtpk(p0, p1), cvtpk(p2, p3));
        }
        ls += __shfl_xor(ls, 16, 64);
        ls += __shfl_xor(ls, 32, 64);
        l_run += ls;

        // PV: P (same-wave LDS bounce, lgkmcnt-ordered) x V-hi
#pragma unroll
        for (int s = 0; s < 2; ++s) {
            s16x8 pa = *(const s16x8*)&Pl[w][fr][s * 32 + fq * 8];
#pragma unroll
            for (int n = 0; n < 4; ++n) {
                s16x8 vh = *(const s16x8*)&Vhs[buf][n * 16 + fr][swzcol(s, fq, fr)];
                o[n] = mfma16(pa, vh, o[n]);
            }
        }
        __syncthreads();           // all waves done with buf; prefetch drained
        buf ^= 1;
    }
#undef ASTAGE

    float li[4];
#pragma unroll
    for (int j = 0; j < 4; ++j) li[j] = __shfl(l_run, fq * 4 + j, 64);
#pragma unroll
    for (int n = 0; n < 4; ++n)
#pragma unroll
        for (int j = 0; j < 4; ++j) {
            float val = o[n][j] / li[j];
            size_t off = ((size_t)b * SL + q0 + fq * 4 + j) * SD + h * DK + n * 16 + fr;
            unsigned short hi = f2bf(val);
            ctxh[off] = hi;
            ctxl[off] = f2bf(val - bf2f(hi));
        }
}

extern "C" void kernel_launch(void* const* d_in, const int* in_sizes, int n_in,
                              void* d_out, int out_size, void* d_ws, size_t ws_size,
                              hipStream_t stream)
{
    const float* query = (const float*)d_in[0];
    const int* mask = (const int*)d_in[1];
    const float* Wq = (const float*)d_in[2];
    const float* bq = (const float*)d_in[3];
    const float* Wk = (const float*)d_in[4];
    const float* bk = (const float*)d_in[5];
    const float* Wv = (const float*)d_in[6];
    const float* bv = (const float*)d_in[7];
    const float* Wo = (const float*)d_in[8];
    const float* bo = (const float*)d_in[9];
    float* out = (float*)d_out;

    const size_t M = (size_t)SB * SL;           // 4096
    const size_t MD = M * SD;                   // 4 M elems
    const size_t WD = (size_t)SD * SD;          // 1 M elems

    unsigned short* p = (unsigned short*)d_ws;
    unsigned short* queryh = p;  p += MD;
    unsigned short* queryl = p;  p += MD;
    unsigned short* Wqh = p;  p += WD;
    unsigned short* Wql = p;  p += WD;
    unsigned short* Wkh = p;  p += WD;
    unsigned short* Wkl = p;  p += WD;
    unsigned short* Wvh = p;  p += WD;
    unsigned short* Wvl = p;  p += WD;
    unsigned short* Woh = p;  p += WD;
    unsigned short* Wol = p;  p += WD;
    unsigned short* Qh = p;  p += MD;
    unsigned short* Ql = p;  p += MD;
    unsigned short* Kh = p;  p += MD;
    unsigned short* Kl = p;  p += MD;
    unsigned short* Vth = p;  p += MD;
    unsigned* mbits = (unsigned*)p;
    unsigned short* ctxh = queryh;   // alias: query planes consumed before attn writes
    unsigned short* ctxl = queryl;

    SplitArgs S;
    S.src[0] = query; S.h[0] = queryh; S.l[0] = queryl;
    S.src[1] = Wq;    S.h[1] = Wqh;    S.l[1] = Wql;
    S.src[2] = Wk;    S.h[2] = Wkh;    S.l[2] = Wkl;
    S.src[3] = Wv;    S.h[3] = Wvh;    S.l[3] = Wvl;
    S.src[4] = Wo;    S.h[4] = Woh;    S.l[4] = Wol;
    split_all<<<4096, 256, 0, stream>>>(S);

    pack_mask<<<(SL * SL) / 256, 256, 0, stream>>>(mask, mbits);

    QKVArgs A;
    A.Wh[0] = Wqh; A.Wl[0] = Wql; A.bias[0] = bq; A.Ch[0] = Qh;  A.Cl[0] = Ql;
    A.Wh[1] = Wkh; A.Wl[1] = Wkl; A.bias[1] = bk; A.Ch[1] = Kh;  A.Cl[1] = Kl;
    A.Wh[2] = Wvh; A.Wl[2] = Wvl; A.bias[2] = bv; A.Ch[2] = Vth; A.Cl[2] = nullptr;

    dim3 gq(SD / 128, M / 128, 3);
    gemm_qkv<<<gq, 256, 0, stream>>>(queryh, queryl, A, SD);

    attn<<<SB * SH * (SL / 64), 256, 0, stream>>>(Qh, Ql, Kh, Kl, Vth, mbits, ctxh, ctxl);

    dim3 gg(SD / 128, M / 128);
    gemm_o<<<gg, 256, 0, stream>>>(ctxh, ctxl, Woh, Wol, bo, out, SD);
}

// Round 9
// 314.472 us; speedup vs baseline: 2.1688x; 1.1694x over previous
//
#include <hip/hip_runtime.h>
#include <hip/hip_bf16.h>
#include <stdint.h>

// Problem constants (fixed by reference): B=2, L=2048, D=1024, H=16, dk=64
#define SL 2048
#define SD 1024
#define SH 16
#define SB 2
#define DK 64

// scores are computed in exp2-domain: Q pre-scaled by 1/sqrt(dk) * log2(e)
#define QSCALE 0.1803368801111244f
#define NEGBIG -20000.0f

typedef __attribute__((ext_vector_type(4))) float f32x4;
typedef __attribute__((ext_vector_type(8))) short s16x8;   // 8 bf16 = 4 VGPRs
typedef __attribute__((ext_vector_type(4))) unsigned short u16x4;

__device__ __forceinline__ float bf2f(unsigned short u) {
    return __uint_as_float(((unsigned)u) << 16);
}
__device__ __forceinline__ unsigned short f2bf(float f) {
    unsigned u = __float_as_uint(f);
    return (unsigned short)((u + 0x7fffu + ((u >> 16) & 1u)) >> 16);
}
__device__ __forceinline__ f32x4 mfma16(s16x8 a, s16x8 b, f32x4 c) {
    return __builtin_amdgcn_mfma_f32_16x16x32_bf16(a, b, c, 0, 0, 0);
}
// async global->LDS, 16B/lane; LDS dest = wave-uniform base + lane*16
__device__ __forceinline__ void gl16(const unsigned short* g, unsigned short* l) {
    __builtin_amdgcn_global_load_lds(
        (const __attribute__((address_space(1))) unsigned int*)g,
        (__attribute__((address_space(3))) unsigned int*)l, 16, 0, 0);
}
// pack 2 f32 -> 2 bf16 in one u32 (lo = a, hi = b), RNE
__device__ __forceinline__ unsigned cvtpk(float a, float b) {
    unsigned r;
    asm("v_cvt_pk_bf16_f32 %0, %1, %2" : "=v"(r) : "v"(a), "v"(b));
    return r;
}
// build hi/lo bf16 fragments from 8 f32: hi+lo reproduces x to ~2^-17 rel
__device__ __forceinline__ void mk_hilo(f32x4 a, f32x4 b, s16x8& h, s16x8& l) {
#pragma unroll
    for (int i = 0; i < 4; ++i) {
        unsigned short ha = f2bf(a[i]);
        h[i] = (short)ha;  l[i] = (short)f2bf(a[i] - bf2f(ha));
        unsigned short hb = f2bf(b[i]);
        h[i + 4] = (short)hb;  l[i + 4] = (short)f2bf(b[i] - bf2f(hb));
    }
}
// XCD-aware block swizzle (bijective: total blocks % 8 == 0)
__device__ __forceinline__ void xcd_map(int& bx, int& by) {
    int nx = gridDim.x, n = nx * gridDim.y;
    int f = blockIdx.y * nx + blockIdx.x;
    int v = (f & 7) * (n >> 3) + (f >> 3);
    bx = v % nx;  by = v / nx;
}

// ---------------- fused f32 -> (hi,lo) planes for query + 4 weights ---------
struct SplitArgs {
    const float* src[5];
    unsigned short* h[5];
    unsigned short* l[5];
};
__global__ void split_all(SplitArgs S) {
    int i = blockIdx.x * blockDim.x + threadIdx.x;   // 8-elem units
    int z, off;
    if (i < (1 << 19)) { z = 0; off = i; }                       // query: 4M elems
    else { int j = i - (1 << 19); z = 1 + (j >> 17); off = j & ((1 << 17) - 1); }
    const float* p = S.src[z] + (size_t)off * 8;
    f32x4 a = *(const f32x4*)p, b = *(const f32x4*)(p + 4);
    s16x8 hh, ll;
    mk_hilo(a, b, hh, ll);
    *(s16x8*)(S.h[z] + (size_t)off * 8) = hh;
    *(s16x8*)(S.l[z] + (size_t)off * 8) = ll;
}

// ---------------- mask packing: int32 [L][L] -> bitmask [L][L/32] ----------
__global__ void pack_mask(const int* __restrict__ m, unsigned* __restrict__ bits) {
    long i = (long)blockIdx.x * blockDim.x + threadIdx.x;
    bool v = (m[i] != 0);
    unsigned long long bal = __ballot(v);
    int lane = threadIdx.x & 63;
    if ((lane & 31) == 0) bits[i >> 5] = (unsigned)(bal >> (lane & 32));
}

// ------- shared GEMM core: 128x128 tile, gl16 dbuf, T2-swizzled LDS --------
template <int BK, typename Epi>
__device__ __forceinline__ void gemm_core(
    const unsigned short* __restrict__ Ah_g, const unsigned short* __restrict__ Al_g,
    const unsigned short* __restrict__ Bh_g, const unsigned short* __restrict__ Bl_g,
    int K, int row0, int col0, Epi&& epi)
{
    __shared__ unsigned short Ahs[2][128][BK], Als[2][128][BK];
    __shared__ unsigned short Bhs[2][128][BK], Bls[2][128][BK];
    constexpr int GR = BK / 8;          // 16B granules per LDS row
    constexpr int RPG = 64 / GR;        // rows covered by one gl16
    const int tid = threadIdx.x;
    const int lane = tid & 63, w = tid >> 6;
    const int fr = lane & 15, fq = lane >> 4;
    const int moff = (w >> 1) * 64, noff = (w & 1) * 64;
    const int lrow = lane / GR;
    const int lg = (lane % GR) ^ (lrow & (GR - 1));   // pre-swizzled source granule
    f32x4 acc[4][4] = {};

    auto stage = [&](int buf, int kt) {
#pragma unroll
        for (int i = 0; i < 32 / RPG; ++i) {
            int r0 = w * 32 + i * RPG;               // wave-uniform LDS row base
            size_t ga = (size_t)(row0 + r0 + lrow) * K + kt + lg * 8;
            size_t gb = (size_t)(col0 + r0 + lrow) * K + kt + lg * 8;
            gl16(&Ah_g[ga], &Ahs[buf][r0][0]);
            gl16(&Al_g[ga], &Als[buf][r0][0]);
            gl16(&Bh_g[gb], &Bhs[buf][r0][0]);
            gl16(&Bl_g[gb], &Bls[buf][r0][0]);
        }
    };

    stage(0, 0);
    __syncthreads();
    const int nk = K / BK;
    for (int t = 0; t < nk; ++t) {
        const int buf = t & 1;
        if (t + 1 < nk) stage(buf ^ 1, (t + 1) * BK);
#pragma unroll
        for (int s = 0; s < BK / 32; ++s) {
            s16x8 ah[4], al[4], bh[4], bl[4];
#pragma unroll
            for (int m = 0; m < 4; ++m) {
                int row = moff + m * 16 + fr;
                int col = ((s * 4 + fq) ^ (fr & (GR - 1))) * 8;   // T2 swizzled read
                ah[m] = *(const s16x8*)&Ahs[buf][row][col];
                al[m] = *(const s16x8*)&Als[buf][row][col];
            }
#pragma unroll
            for (int n = 0; n < 4; ++n) {
                int row = noff + n * 16 + fr;
                int col = ((s * 4 + fq) ^ (fr & (GR - 1))) * 8;
                bh[n] = *(const s16x8*)&Bhs[buf][row][col];
                bl[n] = *(const s16x8*)&Bls[buf][row][col];
            }
#pragma unroll
            for (int m = 0; m < 4; ++m)
#pragma unroll
                for (int n = 0; n < 4; ++n) {
                    acc[m][n] = mfma16(ah[m], bh[n], acc[m][n]);
                    acc[m][n] = mfma16(ah[m], bl[n], acc[m][n]);
                    acc[m][n] = mfma16(al[m], bh[n], acc[m][n]);
                }
        }
        __syncthreads();
    }
    epi(acc, row0 + moff, col0 + noff, fr, fq);
}

struct QKVArgs {
    const unsigned short* Wh[3];
    const unsigned short* Wl[3];
    const float* bias[3];
    unsigned short* Ch[3];
    unsigned short* Cl[3];   // Cl[1], Cl[2] unused (K and V are hi-only)
};

// fused Q/K/V projection: blockIdx.z selects weights + epilogue
__global__ __launch_bounds__(256) void gemm_qkv(
    const unsigned short* __restrict__ Ah_g, const unsigned short* __restrict__ Al_g,
    QKVArgs A, int K)
{
    int bx, by;  xcd_map(bx, by);
    const int z = blockIdx.z;
    const float* bias = A.bias[z];
    unsigned short* Ch = A.Ch[z];
    unsigned short* Cl = A.Cl[z];
    gemm_core<32>(Ah_g, Al_g, A.Wh[z], A.Wl[z], K, by * 128, bx * 128,
        [&](f32x4 (&acc)[4][4], int rbase, int cbase, int fr, int fq) {
#pragma unroll
            for (int n = 0; n < 4; ++n) {
                int c = cbase + n * 16 + fr;
                float bv = bias[c];
#pragma unroll
                for (int m = 0; m < 4; ++m) {
                    int r = rbase + m * 16 + fq * 4;
                    if (z == 2) {   // V: transposed hi-only planes [b][col][tok]
                        u16x4 hv;
#pragma unroll
                        for (int j = 0; j < 4; ++j) hv[j] = f2bf(acc[m][n][j] + bv);
                        int b_ = r >> 11, tok = r & 2047;
                        *(u16x4*)&Ch[((size_t)b_ * SD + c) * SL + tok] = hv;
                    } else if (z == 1) {  // K: hi-only plane (2-term QK approx)
#pragma unroll
                        for (int j = 0; j < 4; ++j)
                            Ch[(size_t)(r + j) * SD + c] = f2bf(acc[m][n][j] + bv);
                    } else {        // Q: hi/lo planes, pre-scaled to exp2 domain
#pragma unroll
                        for (int j = 0; j < 4; ++j) {
                            float val = (acc[m][n][j] + bv) * QSCALE;
                            unsigned short hi = f2bf(val);
                            size_t o = (size_t)(r + j) * SD + c;
                            Ch[o] = hi;
                            Cl[o] = f2bf(val - bf2f(hi));
                        }
                    }
                }
            }
        });
}

// output projection: f32 result
__global__ __launch_bounds__(256) void gemm_o(
    const unsigned short* __restrict__ Ah_g, const unsigned short* __restrict__ Al_g,
    const unsigned short* __restrict__ Bh_g, const unsigned short* __restrict__ Bl_g,
    const float* __restrict__ bias, float* __restrict__ Cf, int K)
{
    int bx, by;  xcd_map(bx, by);
    gemm_core<64>(Ah_g, Al_g, Bh_g, Bl_g, K, by * 128, bx * 128,
        [&](f32x4 (&acc)[4][4], int rbase, int cbase, int fr, int fq) {
#pragma unroll
            for (int n = 0; n < 4; ++n) {
                int c = cbase + n * 16 + fr;
                float bv = bias[c];
#pragma unroll
                for (int m = 0; m < 4; ++m) {
                    int r = rbase + m * 16 + fq * 4;
#pragma unroll
                    for (int j = 0; j < 4; ++j)
                        Cf[(size_t)(r + j) * SD + c] = acc[m][n][j] + bv;
                }
            }
        });
}

// swizzled fragment column (in shorts) within a 64-short (8-granule) row
__device__ __forceinline__ int swzcol(int s, int fq, int fr) {
    return (((s << 2) | fq) ^ (fr & 7)) << 3;
}

// ---------------- flash attention, fixed-shift softmax ----------------------
// 8 waves/block (512 thr), wave owns 16 q rows, block covers 128 q rows.
// Softmax is exact shift-invariant with shift=0: P = exp2(s); no max tracking.
__global__ __launch_bounds__(512) void attn(
    const unsigned short* __restrict__ Qh_g, const unsigned short* __restrict__ Ql_g,
    const unsigned short* __restrict__ Kh_g,
    const unsigned short* __restrict__ Vth_g,
    const unsigned* __restrict__ mbits,
    unsigned short* __restrict__ ctxh, unsigned short* __restrict__ ctxl)
{
    __shared__ unsigned short Khs[2][64][64], Vhs[2][64][64];
    __shared__ unsigned short Pl[8][16][72];            // per-wave P tile (padded)

    const int tid = threadIdx.x;
    const int lane = tid & 63, w = tid >> 6;
    const int fr = lane & 15, fq = lane >> 4;

    const int bid0 = blockIdx.x;
    const int bid = (bid0 & 7) * 64 + (bid0 >> 3);      // XCD swizzle (512 blocks)
    const int nq = SL / 128;                            // 16 q-blocks per (b,h)
    const int qb = bid % nq;
    const int bh_ = bid / nq;
    const int h = bh_ % SH, b = bh_ / SH;

    const int q0 = qb * 128 + w * 16;
    const int qrow = q0 + fr;
    const size_t qg = ((size_t)b * SL + qrow) * SD + h * DK;
    s16x8 qh0 = *(const s16x8*)&Qh_g[qg + fq * 8];
    s16x8 qh1 = *(const s16x8*)&Qh_g[qg + 32 + fq * 8];
    s16x8 ql0 = *(const s16x8*)&Ql_g[qg + fq * 8];
    s16x8 ql1 = *(const s16x8*)&Ql_g[qg + 32 + fq * 8];

    f32x4 o[4] = {};
    float l_run = 0.f;
    const unsigned* mrow = mbits + (size_t)qrow * (SL >> 5);

    const int srow = lane >> 3;                       // 0..7
    const int scolS = ((lane & 7) ^ srow) << 3;       // pre-swizzled src col (shorts)

    // 16 gl16 units/tile (2 planes x 8 row-groups); wave w does units w, w+8
#define ASTAGE(buf, kv)                                                       \
    {                                                                         \
        int r0 = w * 8;                                                       \
        int rr = r0 + srow;                                                   \
        size_t gk = ((size_t)b * SL + (kv) + rr) * SD + h * DK + scolS;       \
        gl16(&Kh_g[gk], &Khs[buf][r0][0]);                                    \
        size_t gv = ((size_t)b * SD + h * DK + rr) * SL + (kv) + scolS;       \
        gl16(&Vth_g[gv], &Vhs[buf][r0][0]);                                   \
    }

    ASTAGE(0, 0);
    __syncthreads();
    int buf = 0;
    for (int kv = 0; kv < SL; kv += 64) {
        if (kv + 64 < SL) ASTAGE(buf ^ 1, kv + 64);    // prefetch next tile

        // S^T tile: mfma(A=K rows, B=Q^T) -> lane holds q=fr, k = 16t + fq*4 + j
        f32x4 st[4];
#pragma unroll
        for (int t = 0; t < 4; ++t) {
            const unsigned short* kb = &Khs[buf][t * 16 + fr][0];
            s16x8 kh0 = *(const s16x8*)&kb[swzcol(0, fq, fr)];
            s16x8 kh1 = *(const s16x8*)&kb[swzcol(1, fq, fr)];
            f32x4 z = {};
            z = mfma16(kh0, qh0, z);
            z = mfma16(kh1, qh1, z);
            z = mfma16(kh0, ql0, z);
            z = mfma16(kh1, ql1, z);
            st[t] = z;
        }

        unsigned mw0 = mrow[kv >> 5];
        unsigned mw1 = mrow[(kv >> 5) + 1];
        // P = exp2(s) directly (shift-invariant softmax, shift = 0; masked -> 0)
#pragma unroll
        for (int t = 0; t < 4; ++t) {
            int kbase = t * 16 + fq * 4;
            unsigned word = (kbase & 32) ? mw1 : mw0;
            float p0 = exp2f(((word >> ((kbase + 0) & 31)) & 1u) ? st[t][0] : NEGBIG);
            float p1 = exp2f(((word >> ((kbase + 1) & 31)) & 1u) ? st[t][1] : NEGBIG);
            float p2 = exp2f(((word >> ((kbase + 2) & 31)) & 1u) ? st[t][2] : NEGBIG);
            float p3 = exp2f(((word >> ((kbase + 3) & 31)) & 1u) ? st[t][3] : NEGBIG);
            l_run += (p0 + p1) + (p2 + p3);
            *(uint2*)&Pl[w][fr][t * 16 + fq * 4] = make_uint2(cvtpk(p0, p1), cvtpk(p2, p3));
        }

        // PV: P (same-wave LDS bounce, lgkmcnt-ordered) x V-hi
#pragma unroll
        for (int s = 0; s < 2; ++s) {
            s16x8 pa = *(const s16x8*)&Pl[w][fr][s * 32 + fq * 8];
#pragma unroll
            for (int n = 0; n < 4; ++n) {
                s16x8 vh = *(const s16x8*)&Vhs[buf][n * 16 + fr][swzcol(s, fq, fr)];
                o[n] = mfma16(pa, vh, o[n]);
            }
        }
        __syncthreads();           // all waves done with buf; prefetch drained
        buf ^= 1;
    }
#undef ASTAGE

    l_run += __shfl_xor(l_run, 16, 64);
    l_run += __shfl_xor(l_run, 32, 64);
    float li[4];
#pragma unroll
    for (int j = 0; j < 4; ++j) li[j] = __shfl(l_run, fq * 4 + j, 64);
#pragma unroll
    for (int n = 0; n < 4; ++n)
#pragma unroll
        for (int j = 0; j < 4; ++j) {
            float val = o[n][j] / li[j];
            size_t off = ((size_t)b * SL + q0 + fq * 4 + j) * SD + h * DK + n * 16 + fr;
            unsigned short hi = f2bf(val);
            ctxh[off] = hi;
            ctxl[off] = f2bf(val - bf2f(hi));
        }
}

extern "C" void kernel_launch(void* const* d_in, const int* in_sizes, int n_in,
                              void* d_out, int out_size, void* d_ws, size_t ws_size,
                              hipStream_t stream)
{
    const float* query = (const float*)d_in[0];
    const int* mask = (const int*)d_in[1];
    const float* Wq = (const float*)d_in[2];
    const float* bq = (const float*)d_in[3];
    const float* Wk = (const float*)d_in[4];
    const float* bk = (const float*)d_in[5];
    const float* Wv = (const float*)d_in[6];
    const float* bv = (const float*)d_in[7];
    const float* Wo = (const float*)d_in[8];
    const float* bo = (const float*)d_in[9];
    float* out = (float*)d_out;

    const size_t M = (size_t)SB * SL;           // 4096
    const size_t MD = M * SD;                   // 4 M elems
    const size_t WD = (size_t)SD * SD;          // 1 M elems

    unsigned short* p = (unsigned short*)d_ws;
    unsigned short* queryh = p;  p += MD;
    unsigned short* queryl = p;  p += MD;
    unsigned short* Wqh = p;  p += WD;
    unsigned short* Wql = p;  p += WD;
    unsigned short* Wkh = p;  p += WD;
    unsigned short* Wkl = p;  p += WD;
    unsigned short* Wvh = p;  p += WD;
    unsigned short* Wvl = p;  p += WD;
    unsigned short* Woh = p;  p += WD;
    unsigned short* Wol = p;  p += WD;
    unsigned short* Qh = p;  p += MD;
    unsigned short* Ql = p;  p += MD;
    unsigned short* Kh = p;  p += MD;
    unsigned short* Vth = p;  p += MD;
    unsigned* mbits = (unsigned*)p;
    unsigned short* ctxh = queryh;   // alias: query planes consumed before attn writes
    unsigned short* ctxl = queryl;

    SplitArgs S;
    S.src[0] = query; S.h[0] = queryh; S.l[0] = queryl;
    S.src[1] = Wq;    S.h[1] = Wqh;    S.l[1] = Wql;
    S.src[2] = Wk;    S.h[2] = Wkh;    S.l[2] = Wkl;
    S.src[3] = Wv;    S.h[3] = Wvh;    S.l[3] = Wvl;
    S.src[4] = Wo;    S.h[4] = Woh;    S.l[4] = Wol;
    split_all<<<4096, 256, 0, stream>>>(S);

    pack_mask<<<(SL * SL) / 256, 256, 0, stream>>>(mask, mbits);

    QKVArgs A;
    A.Wh[0] = Wqh; A.Wl[0] = Wql; A.bias[0] = bq; A.Ch[0] = Qh;  A.Cl[0] = Ql;
    A.Wh[1] = Wkh; A.Wl[1] = Wkl; A.bias[1] = bk; A.Ch[1] = Kh;  A.Cl[1] = nullptr;
    A.Wh[2] = Wvh; A.Wl[2] = Wvl; A.bias[2] = bv; A.Ch[2] = Vth; A.Cl[2] = nullptr;

    dim3 gq(SD / 128, M / 128, 3);
    gemm_qkv<<<gq, 256, 0, stream>>>(queryh, queryl, A, SD);

    attn<<<SB * SH * (SL / 128), 512, 0, stream>>>(Qh, Ql, Kh, Vth, mbits, ctxh, ctxl);

    dim3 gg(SD / 128, M / 128);
    gemm_o<<<gg, 256, 0, stream>>>(ctxh, ctxl, Woh, Wol, bo, out, SD);
}

// Round 11
// 270.687 us; speedup vs baseline: 2.5196x; 1.1618x over previous
//
#include <hip/hip_runtime.h>
#include <hip/hip_bf16.h>
#include <stdint.h>

// Problem constants (fixed by reference): B=2, L=2048, D=1024, H=16, dk=64
#define SL 2048
#define SD 1024
#define SH 16
#define SB 2
#define DK 64

// scores are computed in exp2-domain: Q pre-scaled by 1/sqrt(dk) * log2(e)
#define QSCALE 0.1803368801111244f
#define NEGBIG -20000.0f

typedef __attribute__((ext_vector_type(4))) float f32x4;
typedef __attribute__((ext_vector_type(8))) short s16x8;   // 8 bf16 = 4 VGPRs
typedef __attribute__((ext_vector_type(4))) unsigned short u16x4;

__device__ __forceinline__ float bf2f(unsigned short u) {
    return __uint_as_float(((unsigned)u) << 16);
}
__device__ __forceinline__ unsigned short f2bf(float f) {
    unsigned u = __float_as_uint(f);
    return (unsigned short)((u + 0x7fffu + ((u >> 16) & 1u)) >> 16);
}
__device__ __forceinline__ f32x4 mfma16(s16x8 a, s16x8 b, f32x4 c) {
    return __builtin_amdgcn_mfma_f32_16x16x32_bf16(a, b, c, 0, 0, 0);
}
// async global->LDS, 16B/lane; LDS dest = wave-uniform base + lane*16
__device__ __forceinline__ void gl16(const unsigned short* g, unsigned short* l) {
    __builtin_amdgcn_global_load_lds(
        (const __attribute__((address_space(1))) unsigned int*)g,
        (__attribute__((address_space(3))) unsigned int*)l, 16, 0, 0);
}
// pack 2 f32 -> 2 bf16 in one u32 (lo = a, hi = b), RNE
__device__ __forceinline__ unsigned cvtpk(float a, float b) {
    unsigned r;
    asm("v_cvt_pk_bf16_f32 %0, %1, %2" : "=v"(r) : "v"(a), "v"(b));
    return r;
}
// build hi/lo bf16 fragments from 8 f32: hi+lo reproduces x to ~2^-17 rel
__device__ __forceinline__ void mk_hilo(f32x4 a, f32x4 b, s16x8& h, s16x8& l) {
#pragma unroll
    for (int i = 0; i < 4; ++i) {
        unsigned short ha = f2bf(a[i]);
        h[i] = (short)ha;  l[i] = (short)f2bf(a[i] - bf2f(ha));
        unsigned short hb = f2bf(b[i]);
        h[i + 4] = (short)hb;  l[i + 4] = (short)f2bf(b[i] - bf2f(hb));
    }
}
// XCD-aware block swizzle (bijective: total blocks % 8 == 0)
__device__ __forceinline__ void xcd_map(int& bx, int& by) {
    int nx = gridDim.x, n = nx * gridDim.y;
    int f = blockIdx.y * nx + blockIdx.x;
    int v = (f & 7) * (n >> 3) + (f >> 3);
    bx = v % nx;  by = v / nx;
}

// ------ fused f32 -> bf16 planes: query hi+lo, weights hi-only --------------
struct SplitArgs {
    const float* src[5];
    unsigned short* h[5];
    unsigned short* l[5];   // l[1..4] == nullptr (weights are hi-only, 2-term GEMM)
};
__global__ void split_all(SplitArgs S) {
    int i = blockIdx.x * blockDim.x + threadIdx.x;   // 8-elem units
    int z, off;
    if (i < (1 << 19)) { z = 0; off = i; }                       // query: 4M elems
    else { int j = i - (1 << 19); z = 1 + (j >> 17); off = j & ((1 << 17) - 1); }
    const float* p = S.src[z] + (size_t)off * 8;
    f32x4 a = *(const f32x4*)p, b = *(const f32x4*)(p + 4);
    s16x8 hh, ll;
    mk_hilo(a, b, hh, ll);
    *(s16x8*)(S.h[z] + (size_t)off * 8) = hh;
    if (z == 0) *(s16x8*)(S.l[z] + (size_t)off * 8) = ll;
}

// ---------------- mask packing: int32 [L][L] -> bitmask [L][L/32] ----------
__global__ void pack_mask(const int* __restrict__ m, unsigned* __restrict__ bits) {
    long i = (long)blockIdx.x * blockDim.x + threadIdx.x;
    bool v = (m[i] != 0);
    unsigned long long bal = __ballot(v);
    int lane = threadIdx.x & 63;
    if ((lane & 31) == 0) bits[i >> 5] = (unsigned)(bal >> (lane & 32));
}

// --- shared GEMM core: 128x128 tile, gl16 dbuf, T2 swizzle, 2-term hi/lo ---
// C = (Ah + Al) @ Bh^T : A-side split, B-side hi-only (err ~0.1% of out RMS)
template <int BK, typename Epi>
__device__ __forceinline__ void gemm_core(
    const unsigned short* __restrict__ Ah_g, const unsigned short* __restrict__ Al_g,
    const unsigned short* __restrict__ Bh_g,
    int K, int row0, int col0, Epi&& epi)
{
    __shared__ unsigned short Ahs[2][128][BK], Als[2][128][BK];
    __shared__ unsigned short Bhs[2][128][BK];
    constexpr int GR = BK / 8;          // 16B granules per LDS row
    constexpr int RPG = 64 / GR;        // rows covered by one gl16
    const int tid = threadIdx.x;
    const int lane = tid & 63, w = tid >> 6;
    const int fr = lane & 15, fq = lane >> 4;
    const int moff = (w >> 1) * 64, noff = (w & 1) * 64;
    const int lrow = lane / GR;
    const int lg = (lane % GR) ^ (lrow & (GR - 1));   // pre-swizzled source granule
    f32x4 acc[4][4] = {};

    auto stage = [&](int buf, int kt) {
#pragma unroll
        for (int i = 0; i < 32 / RPG; ++i) {
            int r0 = w * 32 + i * RPG;               // wave-uniform LDS row base
            size_t ga = (size_t)(row0 + r0 + lrow) * K + kt + lg * 8;
            size_t gb = (size_t)(col0 + r0 + lrow) * K + kt + lg * 8;
            gl16(&Ah_g[ga], &Ahs[buf][r0][0]);
            gl16(&Al_g[ga], &Als[buf][r0][0]);
            gl16(&Bh_g[gb], &Bhs[buf][r0][0]);
        }
    };

    stage(0, 0);
    __syncthreads();
    const int nk = K / BK;
    for (int t = 0; t < nk; ++t) {
        const int buf = t & 1;
        if (t + 1 < nk) stage(buf ^ 1, (t + 1) * BK);
#pragma unroll
        for (int s = 0; s < BK / 32; ++s) {
            s16x8 ah[4], al[4], bh[4];
#pragma unroll
            for (int m = 0; m < 4; ++m) {
                int row = moff + m * 16 + fr;
                int col = ((s * 4 + fq) ^ (fr & (GR - 1))) * 8;   // T2 swizzled read
                ah[m] = *(const s16x8*)&Ahs[buf][row][col];
                al[m] = *(const s16x8*)&Als[buf][row][col];
            }
#pragma unroll
            for (int n = 0; n < 4; ++n) {
                int row = noff + n * 16 + fr;
                int col = ((s * 4 + fq) ^ (fr & (GR - 1))) * 8;
                bh[n] = *(const s16x8*)&Bhs[buf][row][col];
            }
#pragma unroll
            for (int m = 0; m < 4; ++m)
#pragma unroll
                for (int n = 0; n < 4; ++n) {
                    acc[m][n] = mfma16(ah[m], bh[n], acc[m][n]);
                    acc[m][n] = mfma16(al[m], bh[n], acc[m][n]);
                }
        }
        __syncthreads();
    }
    epi(acc, row0 + moff, col0 + noff, fr, fq);
}

struct QKVArgs {
    const unsigned short* Wh[3];
    const float* bias[3];
    unsigned short* Ch[3];
    unsigned short* Cl[3];   // only Cl[0] used (Q hi/lo)
};

// fused Q/K/V projection: blockIdx.z selects weights + epilogue
__global__ __launch_bounds__(256) void gemm_qkv(
    const unsigned short* __restrict__ Ah_g, const unsigned short* __restrict__ Al_g,
    QKVArgs A, int K)
{
    int bx, by;  xcd_map(bx, by);
    const int z = blockIdx.z;
    const float* bias = A.bias[z];
    unsigned short* Ch = A.Ch[z];
    unsigned short* Cl = A.Cl[z];
    gemm_core<32>(Ah_g, Al_g, A.Wh[z], K, by * 128, bx * 128,
        [&](f32x4 (&acc)[4][4], int rbase, int cbase, int fr, int fq) {
#pragma unroll
            for (int n = 0; n < 4; ++n) {
                int c = cbase + n * 16 + fr;
                float bv = bias[c];
#pragma unroll
                for (int m = 0; m < 4; ++m) {
                    int r = rbase + m * 16 + fq * 4;
                    if (z == 2) {   // V: transposed hi-only planes [b][col][tok]
                        u16x4 hv;
#pragma unroll
                        for (int j = 0; j < 4; ++j) hv[j] = f2bf(acc[m][n][j] + bv);
                        int b_ = r >> 11, tok = r & 2047;
                        *(u16x4*)&Ch[((size_t)b_ * SD + c) * SL + tok] = hv;
                    } else if (z == 1) {  // K: hi-only plane (2-term QK approx)
#pragma unroll
                        for (int j = 0; j < 4; ++j)
                            Ch[(size_t)(r + j) * SD + c] = f2bf(acc[m][n][j] + bv);
                    } else {        // Q: hi/lo planes, pre-scaled to exp2 domain
#pragma unroll
                        for (int j = 0; j < 4; ++j) {
                            float val = (acc[m][n][j] + bv) * QSCALE;
                            unsigned short hi = f2bf(val);
                            size_t o = (size_t)(r + j) * SD + c;
                            Ch[o] = hi;
                            Cl[o] = f2bf(val - bf2f(hi));
                        }
                    }
                }
            }
        });
}

// output projection: f32 result
__global__ __launch_bounds__(256) void gemm_o(
    const unsigned short* __restrict__ Ah_g, const unsigned short* __restrict__ Al_g,
    const unsigned short* __restrict__ Bh_g,
    const float* __restrict__ bias, float* __restrict__ Cf, int K)
{
    int bx, by;  xcd_map(bx, by);
    gemm_core<64>(Ah_g, Al_g, Bh_g, K, by * 128, bx * 128,
        [&](f32x4 (&acc)[4][4], int rbase, int cbase, int fr, int fq) {
#pragma unroll
            for (int n = 0; n < 4; ++n) {
                int c = cbase + n * 16 + fr;
                float bv = bias[c];
#pragma unroll
                for (int m = 0; m < 4; ++m) {
                    int r = rbase + m * 16 + fq * 4;
#pragma unroll
                    for (int j = 0; j < 4; ++j)
                        Cf[(size_t)(r + j) * SD + c] = acc[m][n][j] + bv;
                }
            }
        });
}

// swizzled fragment column (in shorts) within a 64-short (8-granule) row
__device__ __forceinline__ int swzcol(int s, int fq, int fr) {
    return (((s << 2) | fq) ^ (fr & 7)) << 3;
}

// ---------------- flash attention, fixed-shift softmax ----------------------
// 8 waves/block (512 thr), wave owns 16 q rows, block covers 128 q rows.
// Softmax is exact shift-invariant with shift=0: P = exp2(s); no max tracking.
__global__ __launch_bounds__(512) void attn(
    const unsigned short* __restrict__ Qh_g, const unsigned short* __restrict__ Ql_g,
    const unsigned short* __restrict__ Kh_g,
    const unsigned short* __restrict__ Vth_g,
    const unsigned* __restrict__ mbits,
    unsigned short* __restrict__ ctxh, unsigned short* __restrict__ ctxl)
{
    __shared__ unsigned short Khs[2][64][64], Vhs[2][64][64];
    __shared__ unsigned short Pl[8][16][72];            // per-wave P tile (padded)

    const int tid = threadIdx.x;
    const int lane = tid & 63, w = tid >> 6;
    const int fr = lane & 15, fq = lane >> 4;

    const int bid0 = blockIdx.x;
    const int bid = (bid0 & 7) * 64 + (bid0 >> 3);      // XCD swizzle (512 blocks)
    const int nq = SL / 128;                            // 16 q-blocks per (b,h)
    const int qb = bid % nq;
    const int bh_ = bid / nq;
    const int h = bh_ % SH, b = bh_ / SH;

    const int q0 = qb * 128 + w * 16;
    const int qrow = q0 + fr;
    const size_t qg = ((size_t)b * SL + qrow) * SD + h * DK;
    s16x8 qh0 = *(const s16x8*)&Qh_g[qg + fq * 8];
    s16x8 qh1 = *(const s16x8*)&Qh_g[qg + 32 + fq * 8];
    s16x8 ql0 = *(const s16x8*)&Ql_g[qg + fq * 8];
    s16x8 ql1 = *(const s16x8*)&Ql_g[qg + 32 + fq * 8];

    f32x4 o[4] = {};
    float l_run = 0.f;
    const unsigned* mrow = mbits + (size_t)qrow * (SL >> 5);

    const int srow = lane >> 3;                       // 0..7
    const int scolS = ((lane & 7) ^ srow) << 3;       // pre-swizzled src col (shorts)

    // 16 gl16 units/tile (2 planes x 8 row-groups); wave w does units w, w+8
#define ASTAGE(buf, kv)                                                       \
    {                                                                         \
        int r0 = w * 8;                                                       \
        int rr = r0 + srow;                                                   \
        size_t gk = ((size_t)b * SL + (kv) + rr) * SD + h * DK + scolS;       \
        gl16(&Kh_g[gk], &Khs[buf][r0][0]);                                    \
        size_t gv = ((size_t)b * SD + h * DK + rr) * SL + (kv) + scolS;       \
        gl16(&Vth_g[gv], &Vhs[buf][r0][0]);                                   \
    }

    ASTAGE(0, 0);
    __syncthreads();
    int buf = 0;
    for (int kv = 0; kv < SL; kv += 64) {
        if (kv + 64 < SL) ASTAGE(buf ^ 1, kv + 64);    // prefetch next tile

        // S^T tile: mfma(A=K rows, B=Q^T) -> lane holds q=fr, k = 16t + fq*4 + j
        f32x4 st[4];
#pragma unroll
        for (int t = 0; t < 4; ++t) {
            const unsigned short* kb = &Khs[buf][t * 16 + fr][0];
            s16x8 kh0 = *(const s16x8*)&kb[swzcol(0, fq, fr)];
            s16x8 kh1 = *(const s16x8*)&kb[swzcol(1, fq, fr)];
            f32x4 z = {};
            z = mfma16(kh0, qh0, z);
            z = mfma16(kh1, qh1, z);
            z = mfma16(kh0, ql0, z);
            z = mfma16(kh1, ql1, z);
            st[t] = z;
        }

        unsigned mw0 = mrow[kv >> 5];
        unsigned mw1 = mrow[(kv >> 5) + 1];
        // P = exp2(s) directly (shift-invariant softmax, shift = 0; masked -> 0)
#pragma unroll
        for (int t = 0; t < 4; ++t) {
            int kbase = t * 16 + fq * 4;
            unsigned word = (kbase & 32) ? mw1 : mw0;
            float p0 = exp2f(((word >> ((kbase + 0) & 31)) & 1u) ? st[t][0] : NEGBIG);
            float p1 = exp2f(((word >> ((kbase + 1) & 31)) & 1u) ? st[t][1] : NEGBIG);
            float p2 = exp2f(((word >> ((kbase + 2) & 31)) & 1u) ? st[t][2] : NEGBIG);
            float p3 = exp2f(((word >> ((kbase + 3) & 31)) & 1u) ? st[t][3] : NEGBIG);
            l_run += (p0 + p1) + (p2 + p3);
            *(uint2*)&Pl[w][fr][t * 16 + fq * 4] = make_uint2(cvtpk(p0, p1), cvtpk(p2, p3));
        }

        // PV: P (same-wave LDS bounce, lgkmcnt-ordered) x V-hi
#pragma unroll
        for (int s = 0; s < 2; ++s) {
            s16x8 pa = *(const s16x8*)&Pl[w][fr][s * 32 + fq * 8];
#pragma unroll
            for (int n = 0; n < 4; ++n) {
                s16x8 vh = *(const s16x8*)&Vhs[buf][n * 16 + fr][swzcol(s, fq, fr)];
                o[n] = mfma16(pa, vh, o[n]);
            }
        }
        __syncthreads();           // all waves done with buf; prefetch drained
        buf ^= 1;
    }
#undef ASTAGE

    l_run += __shfl_xor(l_run, 16, 64);
    l_run += __shfl_xor(l_run, 32, 64);
    float li[4];
#pragma unroll
    for (int j = 0; j < 4; ++j) li[j] = __shfl(l_run, fq * 4 + j, 64);
#pragma unroll
    for (int n = 0; n < 4; ++n)
#pragma unroll
        for (int j = 0; j < 4; ++j) {
            float val = o[n][j] / li[j];
            size_t off = ((size_t)b * SL + q0 + fq * 4 + j) * SD + h * DK + n * 16 + fr;
            unsigned short hi = f2bf(val);
            ctxh[off] = hi;
            ctxl[off] = f2bf(val - bf2f(hi));
        }
}

extern "C" void kernel_launch(void* const* d_in, const int* in_sizes, int n_in,
                              void* d_out, int out_size, void* d_ws, size_t ws_size,
                              hipStream_t stream)
{
    const float* query = (const float*)d_in[0];
    const int* mask = (const int*)d_in[1];
    const float* Wq = (const float*)d_in[2];
    const float* bq = (const float*)d_in[3];
    const float* Wk = (const float*)d_in[4];
    const float* bk = (const float*)d_in[5];
    const float* Wv = (const float*)d_in[6];
    const float* bv = (const float*)d_in[7];
    const float* Wo = (const float*)d_in[8];
    const float* bo = (const float*)d_in[9];
    float* out = (float*)d_out;

    const size_t M = (size_t)SB * SL;           // 4096
    const size_t MD = M * SD;                   // 4 M elems
    const size_t WD = (size_t)SD * SD;          // 1 M elems

    unsigned short* p = (unsigned short*)d_ws;
    unsigned short* queryh = p;  p += MD;
    unsigned short* queryl = p;  p += MD;
    unsigned short* Wqh = p;  p += WD;
    unsigned short* Wkh = p;  p += WD;
    unsigned short* Wvh = p;  p += WD;
    unsigned short* Woh = p;  p += WD;
    unsigned short* Qh = p;  p += MD;
    unsigned short* Ql = p;  p += MD;
    unsigned short* Kh = p;  p += MD;
    unsigned short* Vth = p;  p += MD;
    unsigned* mbits = (unsigned*)p;
    unsigned short* ctxh = queryh;   // alias: query planes consumed before attn writes
    unsigned short* ctxl = queryl;

    SplitArgs S;
    S.src[0] = query; S.h[0] = queryh; S.l[0] = queryl;
    S.src[1] = Wq;    S.h[1] = Wqh;    S.l[1] = nullptr;
    S.src[2] = Wk;    S.h[2] = Wkh;    S.l[2] = nullptr;
    S.src[3] = Wv;    S.h[3] = Wvh;    S.l[3] = nullptr;
    S.src[4] = Wo;    S.h[4] = Woh;    S.l[4] = nullptr;
    split_all<<<4096, 256, 0, stream>>>(S);

    pack_mask<<<(SL * SL) / 256, 256, 0, stream>>>(mask, mbits);

    QKVArgs A;
    A.Wh[0] = Wqh; A.bias[0] = bq; A.Ch[0] = Qh;  A.Cl[0] = Ql;
    A.Wh[1] = Wkh; A.bias[1] = bk; A.Ch[1] = Kh;  A.Cl[1] = nullptr;
    A.Wh[2] = Wvh; A.bias[2] = bv; A.Ch[2] = Vth; A.Cl[2] = nullptr;

    dim3 gq(SD / 128, M / 128, 3);
    gemm_qkv<<<gq, 256, 0, stream>>>(queryh, queryl, A, SD);

    attn<<<SB * SH * (SL / 128), 512, 0, stream>>>(Qh, Ql, Kh, Vth, mbits, ctxh, ctxl);

    dim3 gg(SD / 128, M / 128);
    gemm_o<<<gg, 256, 0, stream>>>(ctxh, ctxl, Woh, bo, out, SD);
}